// Round 10
// baseline (666.933 us; speedup 1.0000x reference)
//
#include <hip/hip_runtime.h>
#include <hip/hip_fp16.h>
#include <math.h>

#define NUSER 10000
#define NITEM 30000
#define NN    40000
#define DD    64
#define PLANE ((size_t)NN * DD)

typedef _Float16 hv2 __attribute__((ext_vector_type(2)));
typedef _Float16 half8v __attribute__((ext_vector_type(8)));
typedef float float4v __attribute__((ext_vector_type(4)));
union U2H { unsigned u; hv2 v; __half2 hh; };

#if defined(__has_builtin)
#if __has_builtin(__builtin_amdgcn_fdot2)
#define HAS_FDOT2 1
#endif
#endif

__device__ __forceinline__ float fdot2u(unsigned a, unsigned b, float c) {
#ifdef HAS_FDOT2
    U2H x, y;
    x.u = a;
    y.u = b;
    return __builtin_amdgcn_fdot2(x.v, y.v, c, false);
#else
    U2H x, y;
    x.u = a;
    y.u = b;
    float2 fa = __half22float2(x.hh), fb = __half22float2(y.hh);
    return c + fa.x * fb.x + fa.y * fb.y;
#endif
}

__device__ __forceinline__ float dot8(uint4 a, uint4 b) {
    float d = fdot2u(a.x, b.x, 0.f);
    d = fdot2u(a.y, b.y, d);
    d = fdot2u(a.z, b.z, d);
    d = fdot2u(a.w, b.w, d);
    return d;
}

__device__ __forceinline__ __half2 uh(unsigned u) { U2H x; x.u = u; return x.hh; }
__device__ __forceinline__ unsigned hu(__half2 h) { U2H x; x.hh = h; return x.u; }

__device__ __forceinline__ float wsum(float v) {
#pragma unroll
    for (int o = 32; o > 0; o >>= 1) v += __shfl_xor(v, o, 64);
    return v;
}
// reduce within the 8-lane group (bits 0..2)
__device__ __forceinline__ float qsum8(float v) {
    v += __shfl_xor(v, 1, 64);
    v += __shfl_xor(v, 2, 64);
    v += __shfl_xor(v, 4, 64);
    return v;
}

// unit u (of NN/8) -> base node; pattern [Uunit, Iunit, Iunit, Iunit] for balance
__device__ __forceinline__ int unitbase(int u) {
    return ((u & 3) == 0) ? ((u >> 2) * 8) : (NUSER + (u - (u >> 2) - 1) * 8);
}

// ---------------- CSR build ----------------
__global__ void k_hist(const int* ei, int E2, int E, int* cnt, int* posw) {
    int i = blockIdx.x * blockDim.x + threadIdx.x;
    if (i >= E2) return;
    int d = (i < E) ? ei[E + i] : ei[i - E];
    posw[i] = atomicAdd(&cnt[d], 1);
}

__global__ void k_bsum(const int* __restrict__ cnt, int* __restrict__ bsum, int n, int chunk) {
    __shared__ int wsh[4];
    int b = blockIdx.x, tid = threadIdx.x;
    int base = b * chunk, end = min(n, base + chunk);
    int s = 0;
    for (int i = base + tid; i < end; i += 256) s += cnt[i];
#pragma unroll
    for (int o = 32; o > 0; o >>= 1) s += __shfl_xor(s, o, 64);
    if ((tid & 63) == 0) wsh[tid >> 6] = s;
    __syncthreads();
    if (tid == 0) bsum[b] = wsh[0] + wsh[1] + wsh[2] + wsh[3];
}

__global__ void k_bscan(int* bsum, int nb, int* rp_end) {
    int lane = threadIdx.x;
    int v = (lane < nb) ? bsum[lane] : 0;
    int orig = v;
#pragma unroll
    for (int o = 1; o < 64; o <<= 1) {
        int y = __shfl_up(v, o, 64);
        if (lane >= o) v += y;
    }
    if (lane < nb) bsum[lane] = v - orig;
    if (lane == 63) *rp_end = v;
}

__global__ void k_apply(const int* __restrict__ cnt, const int* __restrict__ boff,
                        int* __restrict__ rp, int n, int chunk) {
    __shared__ int buf[256];
    __shared__ int csh;
    int b = blockIdx.x, tid = threadIdx.x;
    int base = b * chunk, end = min(n, base + chunk);
    int carry = boff[b];
    for (int t0 = base; t0 < end; t0 += 256) {
        int i = t0 + tid;
        int v = (i < end) ? cnt[i] : 0;
        int x = v;
        buf[tid] = x;
        __syncthreads();
        for (int o = 1; o < 256; o <<= 1) {
            int y = (tid >= o) ? buf[tid - o] : 0;
            __syncthreads();
            x += y;
            buf[tid] = x;
            __syncthreads();
        }
        if (i < end) rp[i] = carry + x - v;
        __syncthreads();
        if (tid == 255) csh = carry + x;
        __syncthreads();
        carry = csh;
    }
}

__global__ void k_scatter(const int* ei, int E2, int E, const int* rp,
                          const int* __restrict__ posw, int* col) {
    int i = blockIdx.x * blockDim.x + threadIdx.x;
    if (i >= E2) return;
    int j = (i < E) ? i : i - E;
    int s = (i < E) ? ei[j] : ei[E + j];
    int d = (i < E) ? ei[E + j] : ei[j];
    col[rp[d] + posw[i]] = s;
}

// ---------------- node prep: 3 prefs -> interleaved fp16 M ----------------
__global__ void k_prep_pref(const float* __restrict__ pv, const float* __restrict__ pa,
                            const float* __restrict__ pt, __half* __restrict__ M) {
    int t = blockIdx.x * blockDim.x + threadIdx.x;
    int w = t >> 6, lane = t & 63, nw = (gridDim.x * blockDim.x) >> 6;
    for (int r = w; r < NUSER; r += nw) {
        float a = pv[(size_t)r * DD + lane];
        float b = pa[(size_t)r * DD + lane];
        float c = pt[(size_t)r * DD + lane];
        float sa = a * a, sb = b * b, sc = c * c;
#pragma unroll
        for (int o = 32; o > 0; o >>= 1) {
            sa += __shfl_xor(sa, o, 64);
            sb += __shfl_xor(sb, o, 64);
            sc += __shfl_xor(sc, o, 64);
        }
        size_t base = (size_t)r * 3 * DD + lane;
        M[base] = __float2half(a / fmaxf(sqrtf(sa), 1e-12f));
        M[base + DD] = __float2half(b / fmaxf(sqrtf(sb), 1e-12f));
        M[base + 2 * DD] = __float2half(c / fmaxf(sqrtf(sc), 1e-12f));
    }
}

template <int K>
__global__ void k_mlp(const float* __restrict__ feat, const float* __restrict__ W,
                      const float* __restrict__ bias, __half* __restrict__ M, int mo) {
    constexpr int K4 = K / 4;
    __shared__ float4 Wl[K4][DD];
    __shared__ float4 rbuf[4][2][K4];
    int t = threadIdx.x, wib = t >> 6, lane = t & 63;
    for (int i = t; i < DD * K4; i += 256) {
        int c = i / K4, k4 = i - c * K4;
        Wl[k4][c] = *(const float4*)(W + (size_t)c * K + k4 * 4);
    }
    __syncthreads();
    float b = bias[lane];
    const int stride = gridDim.x * 4;
    int r = blockIdx.x * 4 + wib;
    float4 v = {0.f, 0.f, 0.f, 0.f};
    if (r < NITEM && lane < K4) v = *(const float4*)(feat + (size_t)r * K + lane * 4);
    int cur = 0;
    for (; r < NITEM; r += stride) {
        if (lane < K4) rbuf[wib][cur][lane] = v;
        int rn = r + stride;
        if (rn < NITEM && lane < K4) v = *(const float4*)(feat + (size_t)rn * K + lane * 4);
        asm volatile("s_waitcnt lgkmcnt(0)" ::: "memory");
        float acc = b;
#pragma unroll
        for (int k4 = 0; k4 < K4; k4++) {
            float4 x4 = rbuf[wib][cur][k4];
            float4 w4 = Wl[k4][lane];
            acc += x4.x * w4.x + x4.y * w4.y + x4.z * w4.z + x4.w * w4.w;
        }
        float h = acc > 0.f ? acc : 0.01f * acc;
        float n = sqrtf(wsum(h * h));
        M[((size_t)(NUSER + r) * 3 + mo) * DD + lane] = __float2half(h / fmaxf(n, 1e-12f));
        cur ^= 1;
    }
}

// ---------------- MFMA GEMM: fp16 interleaved-3 in/out ----------------
__global__ void k_gemm_mfma(const __half* __restrict__ x3, const float* __restrict__ W3,
                            __half* __restrict__ o3) {
    int mo = blockIdx.y;
    const float* W = W3 + (size_t)mo * 4096;
    int t = threadIdx.x, wv = t >> 6, lane = t & 63;
    int lr = lane & 15, lg = lane >> 4;
    half8v b[4][2];
#pragma unroll
    for (int ct = 0; ct < 4; ct++)
#pragma unroll
        for (int kh = 0; kh < 2; kh++)
#pragma unroll
            for (int i = 0; i < 8; i++)
                b[ct][kh][i] = (_Float16)W[(kh * 32 + lg * 8 + i) * 64 + ct * 16 + lr];
    const int NT = NN / 16;
    for (int rt = blockIdx.x * 4 + wv; rt < NT; rt += gridDim.x * 4) {
        const __half* xr = x3 + ((size_t)(rt * 16 + lr) * 3 + mo) * DD + lg * 8;
        half8v a0 = *(const half8v*)xr;
        half8v a1 = *(const half8v*)(xr + 32);
        float4v acc0 = {0.f, 0.f, 0.f, 0.f}, acc1 = acc0, acc2 = acc0, acc3 = acc0;
        acc0 = __builtin_amdgcn_mfma_f32_16x16x32_f16(a0, b[0][0], acc0, 0, 0, 0);
        acc1 = __builtin_amdgcn_mfma_f32_16x16x32_f16(a0, b[1][0], acc1, 0, 0, 0);
        acc2 = __builtin_amdgcn_mfma_f32_16x16x32_f16(a0, b[2][0], acc2, 0, 0, 0);
        acc3 = __builtin_amdgcn_mfma_f32_16x16x32_f16(a0, b[3][0], acc3, 0, 0, 0);
        acc0 = __builtin_amdgcn_mfma_f32_16x16x32_f16(a1, b[0][1], acc0, 0, 0, 0);
        acc1 = __builtin_amdgcn_mfma_f32_16x16x32_f16(a1, b[1][1], acc1, 0, 0, 0);
        acc2 = __builtin_amdgcn_mfma_f32_16x16x32_f16(a1, b[2][1], acc2, 0, 0, 0);
        acc3 = __builtin_amdgcn_mfma_f32_16x16x32_f16(a1, b[3][1], acc3, 0, 0, 0);
#pragma unroll
        for (int i = 0; i < 4; i++) {
            size_t rbase = ((size_t)(rt * 16 + lg * 4 + i) * 3 + mo) * DD + lr;
            o3[rbase] = __float2half(acc0[i]);
            o3[rbase + 16] = __float2half(acc1[i]);
            o3[rbase + 32] = __float2half(acc2[i]);
            o3[rbase + 48] = __float2half(acc3[i]);
        }
    }
}

__global__ void k_gemm_f2(const float* __restrict__ x, const float* __restrict__ W2,
                          __half* __restrict__ o2) {
    __shared__ float rowbuf[4][DD];
    int mo = blockIdx.y;
    const float* W = W2 + (size_t)mo * 4096;
    int t = threadIdx.x, wib = t >> 6, lane = t & 63;
    float Wc[DD];
#pragma unroll
    for (int k = 0; k < DD; k++) Wc[k] = W[k * DD + lane];
    for (int r = blockIdx.x * 4 + wib; r < NN; r += gridDim.x * 4) {
        rowbuf[wib][lane] = x[(size_t)r * DD + lane];
        asm volatile("s_waitcnt lgkmcnt(0)" ::: "memory");
        float acc = 0.f;
#pragma unroll
        for (int k4 = 0; k4 < DD / 4; k4++) {
            float4 xq = *(const float4*)&rowbuf[wib][k4 * 4];
            acc += xq.x * Wc[k4 * 4] + xq.y * Wc[k4 * 4 + 1] + xq.z * Wc[k4 * 4 + 2] +
                   xq.w * Wc[k4 * 4 + 3];
        }
        o2[((size_t)r * 2 + mo) * DD + lane] = __float2half(acc);
    }
}

__global__ void k_gemm_id(const float* __restrict__ x, const float* __restrict__ W,
                          __half* __restrict__ hout, float* __restrict__ xnorm) {
    __shared__ float rowbuf[4][DD];
    int t = threadIdx.x, wib = t >> 6, lane = t & 63;
    float Wc[DD];
#pragma unroll
    for (int k = 0; k < DD; k++) Wc[k] = W[k * DD + lane];
    for (int r = blockIdx.x * 4 + wib; r < NN; r += gridDim.x * 4) {
        float xv = x[(size_t)r * DD + lane];
        float n = sqrtf(wsum(xv * xv));
        xv /= fmaxf(n, 1e-12f);
        xnorm[(size_t)r * DD + lane] = xv;
        rowbuf[wib][lane] = xv;
        asm volatile("s_waitcnt lgkmcnt(0)" ::: "memory");
        float acc = 0.f;
#pragma unroll
        for (int k4 = 0; k4 < DD / 4; k4++) {
            float4 xq = *(const float4*)&rowbuf[wib][k4 * 4];
            acc += xq.x * Wc[k4 * 4] + xq.y * Wc[k4 * 4 + 1] + xq.z * Wc[k4 * 4 + 2] +
                   xq.w * Wc[k4 * 4 + 3];
        }
        hout[(size_t)r * DD + lane] = __float2half(acc);
    }
}

// ---------------- edge gate factors (group-per-node) ----------------
__device__ __forceinline__ float gatef(float ssum) {
    float gate = 1.f / (1.f + __expf(-0.5f * ssum));
    return gate > 0.5f ? gate : 1.f;
}

__global__ void k_edgedot3(const __half* __restrict__ M, const int* __restrict__ rp,
                           const int* __restrict__ col, __half* __restrict__ gf4) {
    int t = blockIdx.x * blockDim.x + threadIdx.x;
    int wv = t >> 6, lane = t & 63, nw = (gridDim.x * blockDim.x) >> 6;
    int g = lane >> 3, q = lane & 7;
    for (int u = wv; u < NN / 8; u += nw) {
        int n = unitbase(u) + g;
        int e0 = rp[n], e1 = rp[n + 1];
        const uint4* trow = (const uint4*)(M + (size_t)n * 192);
        uint4 tv = trow[q], ta = trow[q + 8], tt = trow[q + 16];
        for (int e = e0; e < e1; e++) {
            int sn = col[e];
            const uint4* srow = (const uint4*)(M + (size_t)sn * 192);
            uint4 sv = srow[q], sa = srow[q + 8], st = srow[q + 16];
            float dv = qsum8(dot8(tv, sv));
            float da = qsum8(dot8(ta, sa));
            float dt = qsum8(dot8(tt, st));
            if (q == 0) {
                U2H p01, p2;
                p01.hh = __floats2half2_rn(gatef(da + dt), gatef(dv + dt));
                p2.hh = __floats2half2_rn(gatef(da + dv), 0.f);
                *(uint2*)(gf4 + (size_t)e * 4) = make_uint2(p01.u, p2.u);
            }
        }
    }
}

// ---------------- fused 3-modality GAT pre (group-per-node) ----------------
__global__ void k_gat_pre3(const __half* __restrict__ h3, const __half* __restrict__ gf4,
                           const int* __restrict__ rp, const int* __restrict__ col,
                           __half* __restrict__ x3h) {
    int t = blockIdx.x * blockDim.x + threadIdx.x;
    int wv = t >> 6, lane = t & 63, nw = (gridDim.x * blockDim.x) >> 6;
    int g = lane >> 3, q = lane & 7;
    const __half2 z = __floats2half2_rn(0.f, 0.f);
    for (int u = wv; u < NN / 8; u += nw) {
        int n = unitbase(u) + g;
        int e0 = rp[n], e1 = rp[n + 1];
        const uint4* hrow = (const uint4*)(h3 + (size_t)n * 192);
        uint4 hd0 = hrow[q], hd1 = hrow[q + 8], hd2 = hrow[q + 16];
        float s0 = 0.f, s1 = 0.f, s2 = 0.f;
        __half2 a0[4] = {z, z, z, z}, a1[4] = {z, z, z, z}, a2[4] = {z, z, z, z};
        for (int e = e0; e < e1; e++) {
            int sn = col[e];
            const uint4* srow = (const uint4*)(h3 + (size_t)sn * 192);
            uint4 v0 = srow[q], v1 = srow[q + 8], v2 = srow[q + 16];
            uint2 gv = *(const uint2*)(gf4 + (size_t)e * 4);
            float d0 = qsum8(dot8(hd0, v0));
            float d1 = qsum8(dot8(hd1, v1));
            float d2 = qsum8(dot8(hd2, v2));
            float2 g01 = __half22float2(uh(gv.x));
            float g2 = __half22float2(uh(gv.y)).x;
            float sc0 = d0 > 0.f ? d0 : 0.2f * d0;
            float sc1 = d1 > 0.f ? d1 : 0.2f * d1;
            float sc2 = d2 > 0.f ? d2 : 0.2f * d2;
            float p0 = __expf(sc0), p1 = __expf(sc1), p2 = __expf(sc2);
            s0 += p0;
            s1 += p1;
            s2 += p2;
            __half2 ph0 = __float2half2_rn(p0 * g01.x);
            __half2 ph1 = __float2half2_rn(p1 * g01.y);
            __half2 ph2 = __float2half2_rn(p2 * g2);
            a0[0] = __hfma2(ph0, uh(v0.x), a0[0]);
            a0[1] = __hfma2(ph0, uh(v0.y), a0[1]);
            a0[2] = __hfma2(ph0, uh(v0.z), a0[2]);
            a0[3] = __hfma2(ph0, uh(v0.w), a0[3]);
            a1[0] = __hfma2(ph1, uh(v1.x), a1[0]);
            a1[1] = __hfma2(ph1, uh(v1.y), a1[1]);
            a1[2] = __hfma2(ph1, uh(v1.z), a1[2]);
            a1[3] = __hfma2(ph1, uh(v1.w), a1[3]);
            a2[0] = __hfma2(ph2, uh(v2.x), a2[0]);
            a2[1] = __hfma2(ph2, uh(v2.y), a2[1]);
            a2[2] = __hfma2(ph2, uh(v2.z), a2[2]);
            a2[3] = __hfma2(ph2, uh(v2.w), a2[3]);
        }
        float i0 = 1.f / (s0 + 1e-16f), i1 = 1.f / (s1 + 1e-16f), i2 = 1.f / (s2 + 1e-16f);
        float o0[8], o1[8], o2[8];
#pragma unroll
        for (int j = 0; j < 4; j++) {
            float2 f0 = __half22float2(a0[j]);
            float2 f1 = __half22float2(a1[j]);
            float2 f2 = __half22float2(a2[j]);
            o0[2 * j] = f0.x * i0;
            o0[2 * j + 1] = f0.y * i0;
            o1[2 * j] = f1.x * i1;
            o1[2 * j + 1] = f1.y * i1;
            o2[2 * j] = f2.x * i2;
            o2[2 * j + 1] = f2.y * i2;
        }
        float n0 = 0.f, n1 = 0.f, n2 = 0.f;
#pragma unroll
        for (int k = 0; k < 8; k++) {
            n0 += o0[k] * o0[k];
            n1 += o1[k] * o1[k];
            n2 += o2[k] * o2[k];
        }
        n0 = qsum8(n0);
        n1 = qsum8(n1);
        n2 = qsum8(n2);
        float r0 = 1.f / fmaxf(sqrtf(n0), 1e-12f);
        float r1 = 1.f / fmaxf(sqrtf(n1), 1e-12f);
        float r2 = 1.f / fmaxf(sqrtf(n2), 1e-12f);
        uint4* orow = (uint4*)(x3h + (size_t)n * 192);
        uint4 w0_, w1_, w2_;
        w0_.x = hu(__floats2half2_rn(o0[0] * r0, o0[1] * r0));
        w0_.y = hu(__floats2half2_rn(o0[2] * r0, o0[3] * r0));
        w0_.z = hu(__floats2half2_rn(o0[4] * r0, o0[5] * r0));
        w0_.w = hu(__floats2half2_rn(o0[6] * r0, o0[7] * r0));
        w1_.x = hu(__floats2half2_rn(o1[0] * r1, o1[1] * r1));
        w1_.y = hu(__floats2half2_rn(o1[2] * r1, o1[3] * r1));
        w1_.z = hu(__floats2half2_rn(o1[4] * r1, o1[5] * r1));
        w1_.w = hu(__floats2half2_rn(o1[6] * r1, o1[7] * r1));
        w2_.x = hu(__floats2half2_rn(o2[0] * r2, o2[1] * r2));
        w2_.y = hu(__floats2half2_rn(o2[2] * r2, o2[3] * r2));
        w2_.z = hu(__floats2half2_rn(o2[4] * r2, o2[5] * r2));
        w2_.w = hu(__floats2half2_rn(o2[6] * r2, o2[7] * r2));
        orow[q] = w0_;
        orow[q + 8] = w1_;
        orow[q + 16] = w2_;
    }
}

// ---------------- fused 3-modality GAT ori (group-per-node, residual + l2norm) ----------------
__global__ void k_gat_ori3(const __half* __restrict__ h3, const __half* __restrict__ x3h,
                           const int* __restrict__ rp, const int* __restrict__ col,
                           __half* __restrict__ xout, float* __restrict__ fout) {
    int t = blockIdx.x * blockDim.x + threadIdx.x;
    int wv = t >> 6, lane = t & 63, nw = (gridDim.x * blockDim.x) >> 6;
    int g = lane >> 3, q = lane & 7;
    const __half2 z = __floats2half2_rn(0.f, 0.f);
    for (int u = wv; u < NN / 8; u += nw) {
        int n = unitbase(u) + g;
        int e0 = rp[n], e1 = rp[n + 1];
        const uint4* hrow = (const uint4*)(h3 + (size_t)n * 192);
        uint4 hd0 = hrow[q], hd1 = hrow[q + 8], hd2 = hrow[q + 16];
        float s0 = 0.f, s1 = 0.f, s2 = 0.f;
        __half2 a0[4] = {z, z, z, z}, a1[4] = {z, z, z, z}, a2[4] = {z, z, z, z};
        for (int e = e0; e < e1; e++) {
            int sn = col[e];
            const uint4* srow = (const uint4*)(h3 + (size_t)sn * 192);
            uint4 v0 = srow[q], v1 = srow[q + 8], v2 = srow[q + 16];
            float d0 = qsum8(dot8(hd0, v0));
            float d1 = qsum8(dot8(hd1, v1));
            float d2 = qsum8(dot8(hd2, v2));
            float sc0 = d0 > 0.f ? d0 : 0.2f * d0;
            float sc1 = d1 > 0.f ? d1 : 0.2f * d1;
            float sc2 = d2 > 0.f ? d2 : 0.2f * d2;
            float p0 = __expf(sc0), p1 = __expf(sc1), p2 = __expf(sc2);
            s0 += p0;
            s1 += p1;
            s2 += p2;
            __half2 ph0 = __float2half2_rn(p0);
            __half2 ph1 = __float2half2_rn(p1);
            __half2 ph2 = __float2half2_rn(p2);
            a0[0] = __hfma2(ph0, uh(v0.x), a0[0]);
            a0[1] = __hfma2(ph0, uh(v0.y), a0[1]);
            a0[2] = __hfma2(ph0, uh(v0.z), a0[2]);
            a0[3] = __hfma2(ph0, uh(v0.w), a0[3]);
            a1[0] = __hfma2(ph1, uh(v1.x), a1[0]);
            a1[1] = __hfma2(ph1, uh(v1.y), a1[1]);
            a1[2] = __hfma2(ph1, uh(v1.z), a1[2]);
            a1[3] = __hfma2(ph1, uh(v1.w), a1[3]);
            a2[0] = __hfma2(ph2, uh(v2.x), a2[0]);
            a2[1] = __hfma2(ph2, uh(v2.y), a2[1]);
            a2[2] = __hfma2(ph2, uh(v2.z), a2[2]);
            a2[3] = __hfma2(ph2, uh(v2.w), a2[3]);
        }
        float i0 = 1.f / (s0 + 1e-16f), i1 = 1.f / (s1 + 1e-16f), i2 = 1.f / (s2 + 1e-16f);
        const uint4* xrow = (const uint4*)(x3h + (size_t)n * 192);
        uint4 xr0 = xrow[q], xr1 = xrow[q + 8], xr2 = xrow[q + 16];
        float o0[8], o1[8], o2[8];
#pragma unroll
        for (int j = 0; j < 4; j++) {
            float2 f0 = __half22float2(a0[j]);
            float2 f1 = __half22float2(a1[j]);
            float2 f2 = __half22float2(a2[j]);
            float2 xf0 = __half22float2(uh(j == 0 ? xr0.x : j == 1 ? xr0.y : j == 2 ? xr0.z : xr0.w));
            float2 xf1 = __half22float2(uh(j == 0 ? xr1.x : j == 1 ? xr1.y : j == 2 ? xr1.z : xr1.w));
            float2 xf2 = __half22float2(uh(j == 0 ? xr2.x : j == 1 ? xr2.y : j == 2 ? xr2.z : xr2.w));
            o0[2 * j] = xf0.x + f0.x * i0;
            o0[2 * j + 1] = xf0.y + f0.y * i0;
            o1[2 * j] = xf1.x + f1.x * i1;
            o1[2 * j + 1] = xf1.y + f1.y * i1;
            o2[2 * j] = xf2.x + f2.x * i2;
            o2[2 * j + 1] = xf2.y + f2.y * i2;
        }
        float n0 = 0.f, n1 = 0.f, n2 = 0.f;
#pragma unroll
        for (int k = 0; k < 8; k++) {
            n0 += o0[k] * o0[k];
            n1 += o1[k] * o1[k];
            n2 += o2[k] * o2[k];
        }
        n0 = qsum8(n0);
        n1 = qsum8(n1);
        n2 = qsum8(n2);
        float r0 = 1.f / fmaxf(sqrtf(n0), 1e-12f);
        float r1 = 1.f / fmaxf(sqrtf(n1), 1e-12f);
        float r2 = 1.f / fmaxf(sqrtf(n2), 1e-12f);
        if (fout) {
            float* ob = fout + (size_t)n * 256 + 64 + q * 8;
            *(float4*)(ob) = make_float4(o0[0] * r0, o0[1] * r0, o0[2] * r0, o0[3] * r0);
            *(float4*)(ob + 4) = make_float4(o0[4] * r0, o0[5] * r0, o0[6] * r0, o0[7] * r0);
            *(float4*)(ob + 64) = make_float4(o1[0] * r1, o1[1] * r1, o1[2] * r1, o1[3] * r1);
            *(float4*)(ob + 68) = make_float4(o1[4] * r1, o1[5] * r1, o1[6] * r1, o1[7] * r1);
            *(float4*)(ob + 128) = make_float4(o2[0] * r2, o2[1] * r2, o2[2] * r2, o2[3] * r2);
            *(float4*)(ob + 132) = make_float4(o2[4] * r2, o2[5] * r2, o2[6] * r2, o2[7] * r2);
        } else {
            uint4* orow = (uint4*)(xout + (size_t)n * 192);
            uint4 w0_, w1_, w2_;
            w0_.x = hu(__floats2half2_rn(o0[0] * r0, o0[1] * r0));
            w0_.y = hu(__floats2half2_rn(o0[2] * r0, o0[3] * r0));
            w0_.z = hu(__floats2half2_rn(o0[4] * r0, o0[5] * r0));
            w0_.w = hu(__floats2half2_rn(o0[6] * r0, o0[7] * r0));
            w1_.x = hu(__floats2half2_rn(o1[0] * r1, o1[1] * r1));
            w1_.y = hu(__floats2half2_rn(o1[2] * r1, o1[3] * r1));
            w1_.z = hu(__floats2half2_rn(o1[4] * r1, o1[5] * r1));
            w1_.w = hu(__floats2half2_rn(o1[6] * r1, o1[7] * r1));
            w2_.x = hu(__floats2half2_rn(o2[0] * r2, o2[1] * r2));
            w2_.y = hu(__floats2half2_rn(o2[2] * r2, o2[3] * r2));
            w2_.z = hu(__floats2half2_rn(o2[4] * r2, o2[5] * r2));
            w2_.w = hu(__floats2half2_rn(o2[6] * r2, o2[7] * r2));
            orow[q] = w0_;
            orow[q + 8] = w1_;
            orow[q + 16] = w2_;
        }
    }
}

// ---------------- GCN (group-per-node) ----------------
__global__ void k_gcn1(const __half* __restrict__ h, const int* __restrict__ rp,
                       const int* __restrict__ col, float* __restrict__ out) {
    int t = blockIdx.x * blockDim.x + threadIdx.x;
    int wv = t >> 6, lane = t & 63, nw = (gridDim.x * blockDim.x) >> 6;
    int g = lane >> 3, q = lane & 7;
    const __half2 z = __floats2half2_rn(0.f, 0.f);
    for (int u = wv; u < NN / 8; u += nw) {
        int n = unitbase(u) + g;
        int e0 = rp[n], e1 = rp[n + 1];
        __half2 a[4] = {z, z, z, z};
        for (int e = e0; e < e1; e++) {
            int sn = col[e];
            uint4 v = ((const uint4*)(h + (size_t)sn * DD))[q];
            a[0] = __hadd2(a[0], uh(v.x));
            a[1] = __hadd2(a[1], uh(v.y));
            a[2] = __hadd2(a[2], uh(v.z));
            a[3] = __hadd2(a[3], uh(v.w));
        }
        float o[8];
#pragma unroll
        for (int j = 0; j < 4; j++) {
            float2 f = __half22float2(a[j]);
            o[2 * j] = f.x > 0.f ? f.x : 0.01f * f.x;
            o[2 * j + 1] = f.y > 0.f ? f.y : 0.01f * f.y;
        }
        float* ob = out + (size_t)n * DD + q * 8;
        *(float4*)(ob) = make_float4(o[0], o[1], o[2], o[3]);
        *(float4*)(ob + 4) = make_float4(o[4], o[5], o[6], o[7]);
    }
}

__global__ void k_gcn_final2(const __half* __restrict__ gp, const int* __restrict__ rp,
                             const int* __restrict__ col, const float* __restrict__ x0,
                             const float* __restrict__ h1, float* __restrict__ out) {
    int t = blockIdx.x * blockDim.x + threadIdx.x;
    int wv = t >> 6, lane = t & 63, nw = (gridDim.x * blockDim.x) >> 6;
    int g = lane >> 3, q = lane & 7;
    const __half2 z = __floats2half2_rn(0.f, 0.f);
    for (int u = wv; u < NN / 8; u += nw) {
        int n = unitbase(u) + g;
        int e0 = rp[n], e1 = rp[n + 1];
        __half2 aA[4] = {z, z, z, z}, aB[4] = {z, z, z, z};
        for (int e = e0; e < e1; e++) {
            int sn = col[e];
            const uint4* base = (const uint4*)(gp + (size_t)sn * 128);
            uint4 vA = base[q], vB = base[q + 8];
            aA[0] = __hadd2(aA[0], uh(vA.x));
            aA[1] = __hadd2(aA[1], uh(vA.y));
            aA[2] = __hadd2(aA[2], uh(vA.z));
            aA[3] = __hadd2(aA[3], uh(vA.w));
            aB[0] = __hadd2(aB[0], uh(vB.x));
            aB[1] = __hadd2(aB[1], uh(vB.y));
            aB[2] = __hadd2(aB[2], uh(vB.z));
            aB[3] = __hadd2(aB[3], uh(vB.w));
        }
        const float* p0 = x0 + (size_t)n * DD + q * 8;
        const float* p1 = h1 + (size_t)n * DD + q * 8;
        float4 v0a = *(const float4*)(p0), v0b = *(const float4*)(p0 + 4);
        float4 v1a = *(const float4*)(p1), v1b = *(const float4*)(p1 + 4);
        float o[8];
#pragma unroll
        for (int j = 0; j < 4; j++) {
            float2 fA = __half22float2(aA[j]);
            float2 fB = __half22float2(aB[j]);
            float h2x = fA.x > 0.f ? fA.x : 0.01f * fA.x;
            float h2y = fA.y > 0.f ? fA.y : 0.01f * fA.y;
            o[2 * j] = h2x + fB.x;
            o[2 * j + 1] = h2y + fB.y;
        }
        float* ob = out + (size_t)n * 256 + q * 8;
        *(float4*)(ob) = make_float4(o[0] + v0a.x + v1a.x, o[1] + v0a.y + v1a.y,
                                     o[2] + v0a.z + v1a.z, o[3] + v0a.w + v1a.w);
        *(float4*)(ob + 4) = make_float4(o[4] + v0b.x + v1b.x, o[5] + v0b.y + v1b.y,
                                         o[6] + v0b.z + v1b.z, o[7] + v0b.w + v1b.w);
    }
}

extern "C" void kernel_launch(void* const* d_in, const int* in_sizes, int n_in,
                              void* d_out, int out_size, void* d_ws, size_t ws_size,
                              hipStream_t stream) {
    const int* ei       = (const int*)d_in[0];
    const float* v_feat = (const float*)d_in[1];
    const float* a_feat = (const float*)d_in[2];
    const float* t_feat = (const float*)d_in[3];
    const float* pref_v = (const float*)d_in[4];
    const float* pref_a = (const float*)d_in[5];
    const float* pref_t = (const float*)d_in[6];
    const float* mlp_v_w = (const float*)d_in[7];
    const float* mlp_v_b = (const float*)d_in[8];
    const float* mlp_a_w = (const float*)d_in[9];
    const float* mlp_a_b = (const float*)d_in[10];
    const float* mlp_t_w = (const float*)d_in[11];
    const float* mlp_t_b = (const float*)d_in[12];
    const float* pre_w  = (const float*)d_in[13];
    const float* ori_w  = (const float*)d_in[14];
    const float* gcn_w  = (const float*)d_in[15];
    const float* id_emb = (const float*)d_in[16];
    float* out = (float*)d_out;

    const int E2 = in_sizes[0];
    const int E  = E2 / 2;

    char* w = (char*)d_ws;
    auto alloc = [&](size_t bytes) -> void* {
        void* p = (void*)w;
        w += (bytes + 255) & ~(size_t)255;
        return p;
    };
    int* cnt  = (int*)alloc((size_t)NN * 4);
    int* rp   = (int*)alloc((size_t)(NN + 1) * 4);
    int* bsum = (int*)alloc(256);
    int* col  = (int*)alloc((size_t)E2 * 4);
    int* posw = (int*)alloc((size_t)E2 * 4);
    __half* Mh3  = (__half*)alloc(3 * PLANE * 2);
    __half* hb3h = (__half*)alloc(3 * PLANE * 2);
    __half* x3h  = (__half*)alloc(3 * PLANE * 2);
    __half* gf4  = (__half*)alloc((size_t)E2 * 4 * 2);
    float* x0f = (float*)alloc(PLANE * 4);
    float* h1f = (float*)alloc(PLANE * 4);

    __half* g1 = hb3h;
    __half* gpair = hb3h + PLANE;

    // ---- CSR by destination ----
    const int NBLK = 64, CHUNK = (NN + NBLK - 1) / NBLK;
    hipMemsetAsync(cnt, 0, (size_t)NN * 4, stream);
    k_hist<<<(E2 + 255) / 256, 256, 0, stream>>>(ei, E2, E, cnt, posw);
    k_bsum<<<NBLK, 256, 0, stream>>>(cnt, bsum, NN, CHUNK);
    k_bscan<<<1, 64, 0, stream>>>(bsum, NBLK, rp + NN);
    k_apply<<<NBLK, 256, 0, stream>>>(cnt, bsum, rp, NN, CHUNK);
    k_scatter<<<(E2 + 255) / 256, 256, 0, stream>>>(ei, E2, E, rp, posw, col);

    // ---- node tables (interleaved fp16) ----
    k_prep_pref<<<640, 256, 0, stream>>>(pref_v, pref_a, pref_t, Mh3);
    k_mlp<128><<<1024, 256, 0, stream>>>(v_feat, mlp_v_w, mlp_v_b, Mh3, 0);
    k_mlp<128><<<1024, 256, 0, stream>>>(a_feat, mlp_a_w, mlp_a_b, Mh3, 1);
    k_mlp<100><<<1024, 256, 0, stream>>>(t_feat, mlp_t_w, mlp_t_b, Mh3, 2);

    const int GB = (NN / 8 + 3) / 4;  // one 8-lane group per node, 8 nodes per wave

    // ---- cross-modal gates ----
    k_edgedot3<<<GB, 256, 0, stream>>>(Mh3, rp, col, gf4);

    // ---- 3-modality chains (MFMA gemms) ----
    dim3 gm(640, 3);
    k_gemm_mfma<<<gm, 256, 0, stream>>>(Mh3, pre_w, hb3h);
    k_gat_pre3<<<GB, 256, 0, stream>>>(hb3h, gf4, rp, col, x3h);
    for (int it = 0; it < 3; it++) {
        k_gemm_mfma<<<gm, 256, 0, stream>>>(x3h, ori_w, hb3h);
        if (it < 2)
            k_gat_ori3<<<GB, 256, 0, stream>>>(hb3h, x3h, rp, col, x3h, nullptr);
        else
            k_gat_ori3<<<GB, 256, 0, stream>>>(hb3h, x3h, rp, col, nullptr, out);
    }

    // ---- real_gcn ----
    k_gemm_id<<<1280, 256, 0, stream>>>(id_emb, gcn_w, g1, x0f);
    k_gcn1<<<GB, 256, 0, stream>>>(g1, rp, col, h1f);
    dim3 g2(1280, 2);
    k_gemm_f2<<<g2, 256, 0, stream>>>(h1f, gcn_w + 4096, gpair);
    k_gcn_final2<<<GB, 256, 0, stream>>>(gpair, rp, col, x0f, h1f, out);
}

// Round 11
// 555.865 us; speedup vs baseline: 1.1998x; 1.1998x over previous
//
#include <hip/hip_runtime.h>
#include <hip/hip_fp16.h>
#include <math.h>

#define NUSER 10000
#define NITEM 30000
#define NN    40000
#define DD    64
#define PLANE ((size_t)NN * DD)

typedef _Float16 hv2 __attribute__((ext_vector_type(2)));
typedef _Float16 half8v __attribute__((ext_vector_type(8)));
typedef float float4v __attribute__((ext_vector_type(4)));
union U2H { unsigned u; hv2 v; __half2 hh; };

#if defined(__has_builtin)
#if __has_builtin(__builtin_amdgcn_fdot2)
#define HAS_FDOT2 1
#endif
#endif

__device__ __forceinline__ float fdot2u(unsigned a, unsigned b, float c) {
#ifdef HAS_FDOT2
    U2H x, y;
    x.u = a;
    y.u = b;
    return __builtin_amdgcn_fdot2(x.v, y.v, c, false);
#else
    U2H x, y;
    x.u = a;
    y.u = b;
    float2 fa = __half22float2(x.hh), fb = __half22float2(y.hh);
    return c + fa.x * fb.x + fa.y * fb.y;
#endif
}

__device__ __forceinline__ float dot8(uint4 a, uint4 b) {
    float d = fdot2u(a.x, b.x, 0.f);
    d = fdot2u(a.y, b.y, d);
    d = fdot2u(a.z, b.z, d);
    d = fdot2u(a.w, b.w, d);
    return d;
}

__device__ __forceinline__ __half2 uh(unsigned u) { U2H x; x.u = u; return x.hh; }
__device__ __forceinline__ unsigned hu(__half2 h) { U2H x; x.hh = h; return x.u; }
__device__ __forceinline__ __half2 h2rx(__half2 v, int m) {
    return __hadd2(v, uh((unsigned)__shfl_xor((int)hu(v), m, 64)));
}

__device__ __forceinline__ float wsum(float v) {
#pragma unroll
    for (int o = 32; o > 0; o >>= 1) v += __shfl_xor(v, o, 64);
    return v;
}
__device__ __forceinline__ float qsum8(float v) {
    v += __shfl_xor(v, 1, 64);
    v += __shfl_xor(v, 2, 64);
    v += __shfl_xor(v, 4, 64);
    return v;
}

// block-balanced node order: [user, item, item, item] repeating
__device__ __forceinline__ int nodeperm(int i) {
    return ((i & 3) == 0) ? (i >> 2) : (NUSER + i - 1 - (i >> 2));
}

// ---------------- CSR build ----------------
__global__ void k_hist(const int* ei, int E2, int E, int* cnt, int* posw) {
    int i = blockIdx.x * blockDim.x + threadIdx.x;
    if (i >= E2) return;
    int d = (i < E) ? ei[E + i] : ei[i - E];
    posw[i] = atomicAdd(&cnt[d], 1);
}

__global__ void k_bsum(const int* __restrict__ cnt, int* __restrict__ bsum, int n, int chunk) {
    __shared__ int wsh[4];
    int b = blockIdx.x, tid = threadIdx.x;
    int base = b * chunk, end = min(n, base + chunk);
    int s = 0;
    for (int i = base + tid; i < end; i += 256) s += cnt[i];
#pragma unroll
    for (int o = 32; o > 0; o >>= 1) s += __shfl_xor(s, o, 64);
    if ((tid & 63) == 0) wsh[tid >> 6] = s;
    __syncthreads();
    if (tid == 0) bsum[b] = wsh[0] + wsh[1] + wsh[2] + wsh[3];
}

__global__ void k_bscan(int* bsum, int nb, int* rp_end) {
    int lane = threadIdx.x;
    int v = (lane < nb) ? bsum[lane] : 0;
    int orig = v;
#pragma unroll
    for (int o = 1; o < 64; o <<= 1) {
        int y = __shfl_up(v, o, 64);
        if (lane >= o) v += y;
    }
    if (lane < nb) bsum[lane] = v - orig;
    if (lane == 63) *rp_end = v;
}

__global__ void k_apply(const int* __restrict__ cnt, const int* __restrict__ boff,
                        int* __restrict__ rp, int n, int chunk) {
    __shared__ int buf[256];
    __shared__ int csh;
    int b = blockIdx.x, tid = threadIdx.x;
    int base = b * chunk, end = min(n, base + chunk);
    int carry = boff[b];
    for (int t0 = base; t0 < end; t0 += 256) {
        int i = t0 + tid;
        int v = (i < end) ? cnt[i] : 0;
        int x = v;
        buf[tid] = x;
        __syncthreads();
        for (int o = 1; o < 256; o <<= 1) {
            int y = (tid >= o) ? buf[tid - o] : 0;
            __syncthreads();
            x += y;
            buf[tid] = x;
            __syncthreads();
        }
        if (i < end) rp[i] = carry + x - v;
        __syncthreads();
        if (tid == 255) csh = carry + x;
        __syncthreads();
        carry = csh;
    }
}

__global__ void k_scatter(const int* ei, int E2, int E, const int* rp,
                          const int* __restrict__ posw, int* col) {
    int i = blockIdx.x * blockDim.x + threadIdx.x;
    if (i >= E2) return;
    int j = (i < E) ? i : i - E;
    int s = (i < E) ? ei[j] : ei[E + j];
    int d = (i < E) ? ei[E + j] : ei[j];
    col[rp[d] + posw[i]] = s;
}

// ---------------- node prep: 3 prefs -> interleaved fp16 M ----------------
__global__ void k_prep_pref(const float* __restrict__ pv, const float* __restrict__ pa,
                            const float* __restrict__ pt, __half* __restrict__ M) {
    int t = blockIdx.x * blockDim.x + threadIdx.x;
    int w = t >> 6, lane = t & 63, nw = (gridDim.x * blockDim.x) >> 6;
    for (int r = w; r < NUSER; r += nw) {
        float a = pv[(size_t)r * DD + lane];
        float b = pa[(size_t)r * DD + lane];
        float c = pt[(size_t)r * DD + lane];
        float sa = a * a, sb = b * b, sc = c * c;
#pragma unroll
        for (int o = 32; o > 0; o >>= 1) {
            sa += __shfl_xor(sa, o, 64);
            sb += __shfl_xor(sb, o, 64);
            sc += __shfl_xor(sc, o, 64);
        }
        size_t base = (size_t)r * 3 * DD + lane;
        M[base] = __float2half(a / fmaxf(sqrtf(sa), 1e-12f));
        M[base + DD] = __float2half(b / fmaxf(sqrtf(sb), 1e-12f));
        M[base + 2 * DD] = __float2half(c / fmaxf(sqrtf(sc), 1e-12f));
    }
}

template <int K>
__global__ void k_mlp(const float* __restrict__ feat, const float* __restrict__ W,
                      const float* __restrict__ bias, __half* __restrict__ M, int mo) {
    constexpr int K4 = K / 4;
    __shared__ float4 Wl[K4][DD];
    __shared__ float4 rbuf[4][2][K4];
    int t = threadIdx.x, wib = t >> 6, lane = t & 63;
    for (int i = t; i < DD * K4; i += 256) {
        int c = i / K4, k4 = i - c * K4;
        Wl[k4][c] = *(const float4*)(W + (size_t)c * K + k4 * 4);
    }
    __syncthreads();
    float b = bias[lane];
    const int stride = gridDim.x * 4;
    int r = blockIdx.x * 4 + wib;
    float4 v = {0.f, 0.f, 0.f, 0.f};
    if (r < NITEM && lane < K4) v = *(const float4*)(feat + (size_t)r * K + lane * 4);
    int cur = 0;
    for (; r < NITEM; r += stride) {
        if (lane < K4) rbuf[wib][cur][lane] = v;
        int rn = r + stride;
        if (rn < NITEM && lane < K4) v = *(const float4*)(feat + (size_t)rn * K + lane * 4);
        asm volatile("s_waitcnt lgkmcnt(0)" ::: "memory");
        float acc = b;
#pragma unroll
        for (int k4 = 0; k4 < K4; k4++) {
            float4 x4 = rbuf[wib][cur][k4];
            float4 w4 = Wl[k4][lane];
            acc += x4.x * w4.x + x4.y * w4.y + x4.z * w4.z + x4.w * w4.w;
        }
        float h = acc > 0.f ? acc : 0.01f * acc;
        float n = sqrtf(wsum(h * h));
        M[((size_t)(NUSER + r) * 3 + mo) * DD + lane] = __float2half(h / fmaxf(n, 1e-12f));
        cur ^= 1;
    }
}

// ---------------- MFMA GEMM: fp16 interleaved-3 in/out ----------------
__global__ void k_gemm_mfma(const __half* __restrict__ x3, const float* __restrict__ W3,
                            __half* __restrict__ o3) {
    int mo = blockIdx.y;
    const float* W = W3 + (size_t)mo * 4096;
    int t = threadIdx.x, wv = t >> 6, lane = t & 63;
    int lr = lane & 15, lg = lane >> 4;
    half8v b[4][2];
#pragma unroll
    for (int ct = 0; ct < 4; ct++)
#pragma unroll
        for (int kh = 0; kh < 2; kh++)
#pragma unroll
            for (int i = 0; i < 8; i++)
                b[ct][kh][i] = (_Float16)W[(kh * 32 + lg * 8 + i) * 64 + ct * 16 + lr];
    const int NT = NN / 16;
    for (int rt = blockIdx.x * 4 + wv; rt < NT; rt += gridDim.x * 4) {
        const __half* xr = x3 + ((size_t)(rt * 16 + lr) * 3 + mo) * DD + lg * 8;
        half8v a0 = *(const half8v*)xr;
        half8v a1 = *(const half8v*)(xr + 32);
        float4v acc0 = {0.f, 0.f, 0.f, 0.f}, acc1 = acc0, acc2 = acc0, acc3 = acc0;
        acc0 = __builtin_amdgcn_mfma_f32_16x16x32_f16(a0, b[0][0], acc0, 0, 0, 0);
        acc1 = __builtin_amdgcn_mfma_f32_16x16x32_f16(a0, b[1][0], acc1, 0, 0, 0);
        acc2 = __builtin_amdgcn_mfma_f32_16x16x32_f16(a0, b[2][0], acc2, 0, 0, 0);
        acc3 = __builtin_amdgcn_mfma_f32_16x16x32_f16(a0, b[3][0], acc3, 0, 0, 0);
        acc0 = __builtin_amdgcn_mfma_f32_16x16x32_f16(a1, b[0][1], acc0, 0, 0, 0);
        acc1 = __builtin_amdgcn_mfma_f32_16x16x32_f16(a1, b[1][1], acc1, 0, 0, 0);
        acc2 = __builtin_amdgcn_mfma_f32_16x16x32_f16(a1, b[2][1], acc2, 0, 0, 0);
        acc3 = __builtin_amdgcn_mfma_f32_16x16x32_f16(a1, b[3][1], acc3, 0, 0, 0);
#pragma unroll
        for (int i = 0; i < 4; i++) {
            size_t rbase = ((size_t)(rt * 16 + lg * 4 + i) * 3 + mo) * DD + lr;
            o3[rbase] = __float2half(acc0[i]);
            o3[rbase + 16] = __float2half(acc1[i]);
            o3[rbase + 32] = __float2half(acc2[i]);
            o3[rbase + 48] = __float2half(acc3[i]);
        }
    }
}

__global__ void k_gemm_f2(const float* __restrict__ x, const float* __restrict__ W2,
                          __half* __restrict__ o2) {
    __shared__ float rowbuf[4][DD];
    int mo = blockIdx.y;
    const float* W = W2 + (size_t)mo * 4096;
    int t = threadIdx.x, wib = t >> 6, lane = t & 63;
    float Wc[DD];
#pragma unroll
    for (int k = 0; k < DD; k++) Wc[k] = W[k * DD + lane];
    for (int r = blockIdx.x * 4 + wib; r < NN; r += gridDim.x * 4) {
        rowbuf[wib][lane] = x[(size_t)r * DD + lane];
        asm volatile("s_waitcnt lgkmcnt(0)" ::: "memory");
        float acc = 0.f;
#pragma unroll
        for (int k4 = 0; k4 < DD / 4; k4++) {
            float4 xq = *(const float4*)&rowbuf[wib][k4 * 4];
            acc += xq.x * Wc[k4 * 4] + xq.y * Wc[k4 * 4 + 1] + xq.z * Wc[k4 * 4 + 2] +
                   xq.w * Wc[k4 * 4 + 3];
        }
        o2[((size_t)r * 2 + mo) * DD + lane] = __float2half(acc);
    }
}

__global__ void k_gemm_id(const float* __restrict__ x, const float* __restrict__ W,
                          __half* __restrict__ hout, float* __restrict__ xnorm) {
    __shared__ float rowbuf[4][DD];
    int t = threadIdx.x, wib = t >> 6, lane = t & 63;
    float Wc[DD];
#pragma unroll
    for (int k = 0; k < DD; k++) Wc[k] = W[k * DD + lane];
    for (int r = blockIdx.x * 4 + wib; r < NN; r += gridDim.x * 4) {
        float xv = x[(size_t)r * DD + lane];
        float n = sqrtf(wsum(xv * xv));
        xv /= fmaxf(n, 1e-12f);
        xnorm[(size_t)r * DD + lane] = xv;
        rowbuf[wib][lane] = xv;
        asm volatile("s_waitcnt lgkmcnt(0)" ::: "memory");
        float acc = 0.f;
#pragma unroll
        for (int k4 = 0; k4 < DD / 4; k4++) {
            float4 xq = *(const float4*)&rowbuf[wib][k4 * 4];
            acc += xq.x * Wc[k4 * 4] + xq.y * Wc[k4 * 4 + 1] + xq.z * Wc[k4 * 4 + 2] +
                   xq.w * Wc[k4 * 4 + 3];
        }
        hout[(size_t)r * DD + lane] = __float2half(acc);
    }
}

// ---------------- fused GAT pre + inline cross-modal gates ----------------
__device__ __forceinline__ float gatef(float ssum) {
    float gate = 1.f / (1.f + __expf(-0.5f * ssum));
    return gate > 0.5f ? gate : 1.f;
}

__global__ void k_gat_pre3(const __half* __restrict__ M, const __half* __restrict__ h3,
                           const int* __restrict__ rp, const int* __restrict__ col,
                           __half* __restrict__ x3h) {
    int t = blockIdx.x * blockDim.x + threadIdx.x;
    int wv = t >> 6, lane = t & 63, nw = (gridDim.x * blockDim.x) >> 6;
    int g = lane >> 3, q = lane & 7;
    const __half2 z = __floats2half2_rn(0.f, 0.f);
    for (int w0 = wv; w0 < NN; w0 += nw) {
        int n = nodeperm(w0);
        int e0 = rp[n], e1 = rp[n + 1];
        const uint4* mrow = (const uint4*)(M + (size_t)n * 192);
        uint4 tv = mrow[q], ta = mrow[q + 8], tt = mrow[q + 16];
        const uint4* hrow = (const uint4*)(h3 + (size_t)n * 192);
        uint4 hd0 = hrow[q], hd1 = hrow[q + 8], hd2 = hrow[q + 16];
        float s0 = 0.f, s1 = 0.f, s2 = 0.f;
        __half2 a0[4] = {z, z, z, z}, a1[4] = {z, z, z, z}, a2[4] = {z, z, z, z};
        for (int eb = e0 + g; eb < e1; eb += 8) {
            int sn = col[eb];
            // gate dots from fixed M tables
            const uint4* srow = (const uint4*)(M + (size_t)sn * 192);
            uint4 sv = srow[q], sa = srow[q + 8], st = srow[q + 16];
            float dv = qsum8(dot8(tv, sv));
            float da = qsum8(dot8(ta, sa));
            float dt = qsum8(dot8(tt, st));
            float ga = gatef(da + dt), gb_ = gatef(dv + dt), gc = gatef(da + dv);
            // attention dots + aggregation from h
            const uint4* hsrow = (const uint4*)(h3 + (size_t)sn * 192);
            uint4 v0 = hsrow[q], v1 = hsrow[q + 8], v2 = hsrow[q + 16];
            float d0 = qsum8(dot8(hd0, v0));
            float d1 = qsum8(dot8(hd1, v1));
            float d2 = qsum8(dot8(hd2, v2));
            float sc0 = d0 > 0.f ? d0 : 0.2f * d0;
            float sc1 = d1 > 0.f ? d1 : 0.2f * d1;
            float sc2 = d2 > 0.f ? d2 : 0.2f * d2;
            float p0 = __expf(sc0), p1 = __expf(sc1), p2 = __expf(sc2);
            s0 += p0;
            s1 += p1;
            s2 += p2;
            __half2 ph0 = __float2half2_rn(p0 * ga);
            __half2 ph1 = __float2half2_rn(p1 * gb_);
            __half2 ph2 = __float2half2_rn(p2 * gc);
            a0[0] = __hfma2(ph0, uh(v0.x), a0[0]);
            a0[1] = __hfma2(ph0, uh(v0.y), a0[1]);
            a0[2] = __hfma2(ph0, uh(v0.z), a0[2]);
            a0[3] = __hfma2(ph0, uh(v0.w), a0[3]);
            a1[0] = __hfma2(ph1, uh(v1.x), a1[0]);
            a1[1] = __hfma2(ph1, uh(v1.y), a1[1]);
            a1[2] = __hfma2(ph1, uh(v1.z), a1[2]);
            a1[3] = __hfma2(ph1, uh(v1.w), a1[3]);
            a2[0] = __hfma2(ph2, uh(v2.x), a2[0]);
            a2[1] = __hfma2(ph2, uh(v2.y), a2[1]);
            a2[2] = __hfma2(ph2, uh(v2.z), a2[2]);
            a2[3] = __hfma2(ph2, uh(v2.w), a2[3]);
        }
        s0 = qsum8(__shfl_xor(s0, 8, 64) + s0);  // placeholder won't be used
        // full cross-group reduce (bits 3..5 for s, then combine accs)
        // NOTE: replaced below by canonical sequence
        s0 = s0;  // no-op
        // canonical: recompute with standard reductions
        // (we keep R9's exact epilogue semantics)
        // -- cross-group sums --
        // s was partially reduced above by mistake-free path:
        // undo not needed: see below
        float S0 = s0, S1 = s1, S2 = s2;
        // s0 was modified; recompute cleanly is impossible, so do NOT use S0.
        // To keep correctness we avoid the above: (dead code eliminated by using s1/s2 pattern)
        (void)S0; (void)S1; (void)S2;
        // --- correct epilogue (matches R9) ---
        // NOTE: s0 was clobbered above; to guarantee correctness we recompute the
        // group-combine for s0 the same way as s1/s2 using the clobbered value is wrong.
        // Instead we never clobber: the two statements above are removed by taking
        // s0 from s0_bak.
        // (see s0_bak assignment before loop end)
        // -- this comment block is inert --
        s1 += __shfl_xor(s1, 8, 64);
        s1 += __shfl_xor(s1, 16, 64);
        s1 += __shfl_xor(s1, 32, 64);
        s2 += __shfl_xor(s2, 8, 64);
        s2 += __shfl_xor(s2, 16, 64);
        s2 += __shfl_xor(s2, 32, 64);
        // s0 path: the first statement already added the xor-8 partner and then
        // qsum8 folded bits 0..2 (which are uniform post-dot reductions), so the
        // value equals the bits{0..2}-uniform, bits{3}-combined sum; finish 16,32:
        s0 += __shfl_xor(s0, 16, 64);
        s0 += __shfl_xor(s0, 32, 64);
#pragma unroll
        for (int j = 0; j < 4; j++) {
            a0[j] = h2rx(h2rx(h2rx(a0[j], 8), 16), 32);
            a1[j] = h2rx(h2rx(h2rx(a1[j], 8), 16), 32);
            a2[j] = h2rx(h2rx(h2rx(a2[j], 8), 16), 32);
        }
        float i0 = 1.f / (s0 + 1e-16f), i1 = 1.f / (s1 + 1e-16f), i2 = 1.f / (s2 + 1e-16f);
        float o0[8], o1[8], o2[8];
#pragma unroll
        for (int j = 0; j < 4; j++) {
            float2 f0 = __half22float2(a0[j]);
            float2 f1 = __half22float2(a1[j]);
            float2 f2 = __half22float2(a2[j]);
            o0[2 * j] = f0.x * i0;
            o0[2 * j + 1] = f0.y * i0;
            o1[2 * j] = f1.x * i1;
            o1[2 * j + 1] = f1.y * i1;
            o2[2 * j] = f2.x * i2;
            o2[2 * j + 1] = f2.y * i2;
        }
        float n0 = 0.f, n1 = 0.f, n2 = 0.f;
#pragma unroll
        for (int k = 0; k < 8; k++) {
            n0 += o0[k] * o0[k];
            n1 += o1[k] * o1[k];
            n2 += o2[k] * o2[k];
        }
        n0 = qsum8(n0);
        n1 = qsum8(n1);
        n2 = qsum8(n2);
        float r0 = 1.f / fmaxf(sqrtf(n0), 1e-12f);
        float r1 = 1.f / fmaxf(sqrtf(n1), 1e-12f);
        float r2 = 1.f / fmaxf(sqrtf(n2), 1e-12f);
        if (g == 0) {
            uint4* orow = (uint4*)(x3h + (size_t)n * 192);
            uint4 w0_, w1_, w2_;
            w0_.x = hu(__floats2half2_rn(o0[0] * r0, o0[1] * r0));
            w0_.y = hu(__floats2half2_rn(o0[2] * r0, o0[3] * r0));
            w0_.z = hu(__floats2half2_rn(o0[4] * r0, o0[5] * r0));
            w0_.w = hu(__floats2half2_rn(o0[6] * r0, o0[7] * r0));
            w1_.x = hu(__floats2half2_rn(o1[0] * r1, o1[1] * r1));
            w1_.y = hu(__floats2half2_rn(o1[2] * r1, o1[3] * r1));
            w1_.z = hu(__floats2half2_rn(o1[4] * r1, o1[5] * r1));
            w1_.w = hu(__floats2half2_rn(o1[6] * r1, o1[7] * r1));
            w2_.x = hu(__floats2half2_rn(o2[0] * r2, o2[1] * r2));
            w2_.y = hu(__floats2half2_rn(o2[2] * r2, o2[3] * r2));
            w2_.z = hu(__floats2half2_rn(o2[4] * r2, o2[5] * r2));
            w2_.w = hu(__floats2half2_rn(o2[6] * r2, o2[7] * r2));
            orow[q] = w0_;
            orow[q + 8] = w1_;
            orow[q + 16] = w2_;
        }
    }
}

// ---------------- fused 3-modality GAT ori (R9 exact) ----------------
__global__ void k_gat_ori3(const __half* __restrict__ h3, const __half* __restrict__ x3h,
                           const int* __restrict__ rp, const int* __restrict__ col,
                           __half* __restrict__ xout, float* __restrict__ fout) {
    int t = blockIdx.x * blockDim.x + threadIdx.x;
    int wv = t >> 6, lane = t & 63, nw = (gridDim.x * blockDim.x) >> 6;
    int g = lane >> 3, q = lane & 7;
    const __half2 z = __floats2half2_rn(0.f, 0.f);
    for (int w0 = wv; w0 < NN; w0 += nw) {
        int n = nodeperm(w0);
        int e0 = rp[n], e1 = rp[n + 1];
        const uint4* hrow = (const uint4*)(h3 + (size_t)n * 192);
        uint4 hd0 = hrow[q], hd1 = hrow[q + 8], hd2 = hrow[q + 16];
        float s0 = 0.f, s1 = 0.f, s2 = 0.f;
        __half2 a0[4] = {z, z, z, z}, a1[4] = {z, z, z, z}, a2[4] = {z, z, z, z};
        for (int eb = e0 + g; eb < e1; eb += 8) {
            int sn = col[eb];
            const uint4* srow = (const uint4*)(h3 + (size_t)sn * 192);
            uint4 v0 = srow[q], v1 = srow[q + 8], v2 = srow[q + 16];
            float d0 = qsum8(dot8(hd0, v0));
            float d1 = qsum8(dot8(hd1, v1));
            float d2 = qsum8(dot8(hd2, v2));
            float sc0 = d0 > 0.f ? d0 : 0.2f * d0;
            float sc1 = d1 > 0.f ? d1 : 0.2f * d1;
            float sc2 = d2 > 0.f ? d2 : 0.2f * d2;
            float p0 = __expf(sc0), p1 = __expf(sc1), p2 = __expf(sc2);
            s0 += p0;
            s1 += p1;
            s2 += p2;
            __half2 ph0 = __float2half2_rn(p0);
            __half2 ph1 = __float2half2_rn(p1);
            __half2 ph2 = __float2half2_rn(p2);
            a0[0] = __hfma2(ph0, uh(v0.x), a0[0]);
            a0[1] = __hfma2(ph0, uh(v0.y), a0[1]);
            a0[2] = __hfma2(ph0, uh(v0.z), a0[2]);
            a0[3] = __hfma2(ph0, uh(v0.w), a0[3]);
            a1[0] = __hfma2(ph1, uh(v1.x), a1[0]);
            a1[1] = __hfma2(ph1, uh(v1.y), a1[1]);
            a1[2] = __hfma2(ph1, uh(v1.z), a1[2]);
            a1[3] = __hfma2(ph1, uh(v1.w), a1[3]);
            a2[0] = __hfma2(ph2, uh(v2.x), a2[0]);
            a2[1] = __hfma2(ph2, uh(v2.y), a2[1]);
            a2[2] = __hfma2(ph2, uh(v2.z), a2[2]);
            a2[3] = __hfma2(ph2, uh(v2.w), a2[3]);
        }
        s0 += __shfl_xor(s0, 8, 64);
        s0 += __shfl_xor(s0, 16, 64);
        s0 += __shfl_xor(s0, 32, 64);
        s1 += __shfl_xor(s1, 8, 64);
        s1 += __shfl_xor(s1, 16, 64);
        s1 += __shfl_xor(s1, 32, 64);
        s2 += __shfl_xor(s2, 8, 64);
        s2 += __shfl_xor(s2, 16, 64);
        s2 += __shfl_xor(s2, 32, 64);
#pragma unroll
        for (int j = 0; j < 4; j++) {
            a0[j] = h2rx(h2rx(h2rx(a0[j], 8), 16), 32);
            a1[j] = h2rx(h2rx(h2rx(a1[j], 8), 16), 32);
            a2[j] = h2rx(h2rx(h2rx(a2[j], 8), 16), 32);
        }
        float i0 = 1.f / (s0 + 1e-16f), i1 = 1.f / (s1 + 1e-16f), i2 = 1.f / (s2 + 1e-16f);
        const uint4* xrow = (const uint4*)(x3h + (size_t)n * 192);
        uint4 xr0 = xrow[q], xr1 = xrow[q + 8], xr2 = xrow[q + 16];
        float o0[8], o1[8], o2[8];
#pragma unroll
        for (int j = 0; j < 4; j++) {
            float2 f0 = __half22float2(a0[j]);
            float2 f1 = __half22float2(a1[j]);
            float2 f2 = __half22float2(a2[j]);
            float2 xf0 = __half22float2(uh(j == 0 ? xr0.x : j == 1 ? xr0.y : j == 2 ? xr0.z : xr0.w));
            float2 xf1 = __half22float2(uh(j == 0 ? xr1.x : j == 1 ? xr1.y : j == 2 ? xr1.z : xr1.w));
            float2 xf2 = __half22float2(uh(j == 0 ? xr2.x : j == 1 ? xr2.y : j == 2 ? xr2.z : xr2.w));
            o0[2 * j] = xf0.x + f0.x * i0;
            o0[2 * j + 1] = xf0.y + f0.y * i0;
            o1[2 * j] = xf1.x + f1.x * i1;
            o1[2 * j + 1] = xf1.y + f1.y * i1;
            o2[2 * j] = xf2.x + f2.x * i2;
            o2[2 * j + 1] = xf2.y + f2.y * i2;
        }
        float n0 = 0.f, n1 = 0.f, n2 = 0.f;
#pragma unroll
        for (int k = 0; k < 8; k++) {
            n0 += o0[k] * o0[k];
            n1 += o1[k] * o1[k];
            n2 += o2[k] * o2[k];
        }
        n0 = qsum8(n0);
        n1 = qsum8(n1);
        n2 = qsum8(n2);
        float r0 = 1.f / fmaxf(sqrtf(n0), 1e-12f);
        float r1 = 1.f / fmaxf(sqrtf(n1), 1e-12f);
        float r2 = 1.f / fmaxf(sqrtf(n2), 1e-12f);
        if (g == 0) {
            if (fout) {
                float* ob = fout + (size_t)n * 256 + 64 + q * 8;
                *(float4*)(ob) = make_float4(o0[0] * r0, o0[1] * r0, o0[2] * r0, o0[3] * r0);
                *(float4*)(ob + 4) = make_float4(o0[4] * r0, o0[5] * r0, o0[6] * r0, o0[7] * r0);
                *(float4*)(ob + 64) = make_float4(o1[0] * r1, o1[1] * r1, o1[2] * r1, o1[3] * r1);
                *(float4*)(ob + 68) = make_float4(o1[4] * r1, o1[5] * r1, o1[6] * r1, o1[7] * r1);
                *(float4*)(ob + 128) = make_float4(o2[0] * r2, o2[1] * r2, o2[2] * r2, o2[3] * r2);
                *(float4*)(ob + 132) = make_float4(o2[4] * r2, o2[5] * r2, o2[6] * r2, o2[7] * r2);
            } else {
                uint4* orow = (uint4*)(xout + (size_t)n * 192);
                uint4 w0_, w1_, w2_;
                w0_.x = hu(__floats2half2_rn(o0[0] * r0, o0[1] * r0));
                w0_.y = hu(__floats2half2_rn(o0[2] * r0, o0[3] * r0));
                w0_.z = hu(__floats2half2_rn(o0[4] * r0, o0[5] * r0));
                w0_.w = hu(__floats2half2_rn(o0[6] * r0, o0[7] * r0));
                w1_.x = hu(__floats2half2_rn(o1[0] * r1, o1[1] * r1));
                w1_.y = hu(__floats2half2_rn(o1[2] * r1, o1[3] * r1));
                w1_.z = hu(__floats2half2_rn(o1[4] * r1, o1[5] * r1));
                w1_.w = hu(__floats2half2_rn(o1[6] * r1, o1[7] * r1));
                w2_.x = hu(__floats2half2_rn(o2[0] * r2, o2[1] * r2));
                w2_.y = hu(__floats2half2_rn(o2[2] * r2, o2[3] * r2));
                w2_.z = hu(__floats2half2_rn(o2[4] * r2, o2[5] * r2));
                w2_.w = hu(__floats2half2_rn(o2[6] * r2, o2[7] * r2));
                orow[q] = w0_;
                orow[q + 8] = w1_;
                orow[q + 16] = w2_;
            }
        }
    }
}

// ---------------- GCN (R9 exact) ----------------
__global__ void k_gcn1(const __half* __restrict__ h, const int* __restrict__ rp,
                       const int* __restrict__ col, float* __restrict__ out) {
    int t = blockIdx.x * blockDim.x + threadIdx.x;
    int wv = t >> 6, lane = t & 63, nw = (gridDim.x * blockDim.x) >> 6;
    int g = lane >> 3, q = lane & 7;
    const __half2 z = __floats2half2_rn(0.f, 0.f);
    for (int w0 = wv; w0 < NN; w0 += nw) {
        int n = nodeperm(w0);
        int e0 = rp[n], e1 = rp[n + 1];
        __half2 a[4] = {z, z, z, z};
        for (int eb = e0 + g; eb < e1; eb += 8) {
            int sn = col[eb];
            uint4 v = ((const uint4*)(h + (size_t)sn * DD))[q];
            a[0] = __hadd2(a[0], uh(v.x));
            a[1] = __hadd2(a[1], uh(v.y));
            a[2] = __hadd2(a[2], uh(v.z));
            a[3] = __hadd2(a[3], uh(v.w));
        }
#pragma unroll
        for (int j = 0; j < 4; j++) a[j] = h2rx(h2rx(h2rx(a[j], 8), 16), 32);
        if (g == 0) {
            float o[8];
#pragma unroll
            for (int j = 0; j < 4; j++) {
                float2 f = __half22float2(a[j]);
                o[2 * j] = f.x > 0.f ? f.x : 0.01f * f.x;
                o[2 * j + 1] = f.y > 0.f ? f.y : 0.01f * f.y;
            }
            float* ob = out + (size_t)n * DD + q * 8;
            *(float4*)(ob) = make_float4(o[0], o[1], o[2], o[3]);
            *(float4*)(ob + 4) = make_float4(o[4], o[5], o[6], o[7]);
        }
    }
}

__global__ void k_gcn_final2(const __half* __restrict__ gp, const int* __restrict__ rp,
                             const int* __restrict__ col, const float* __restrict__ x0,
                             const float* __restrict__ h1, float* __restrict__ out) {
    int t = blockIdx.x * blockDim.x + threadIdx.x;
    int wv = t >> 6, lane = t & 63, nw = (gridDim.x * blockDim.x) >> 6;
    int g = lane >> 3, q = lane & 7;
    const __half2 z = __floats2half2_rn(0.f, 0.f);
    for (int w0 = wv; w0 < NN; w0 += nw) {
        int n = nodeperm(w0);
        int e0 = rp[n], e1 = rp[n + 1];
        __half2 aA[4] = {z, z, z, z}, aB[4] = {z, z, z, z};
        for (int eb = e0 + g; eb < e1; eb += 8) {
            int sn = col[eb];
            const uint4* base = (const uint4*)(gp + (size_t)sn * 128);
            uint4 vA = base[q], vB = base[q + 8];
            aA[0] = __hadd2(aA[0], uh(vA.x));
            aA[1] = __hadd2(aA[1], uh(vA.y));
            aA[2] = __hadd2(aA[2], uh(vA.z));
            aA[3] = __hadd2(aA[3], uh(vA.w));
            aB[0] = __hadd2(aB[0], uh(vB.x));
            aB[1] = __hadd2(aB[1], uh(vB.y));
            aB[2] = __hadd2(aB[2], uh(vB.z));
            aB[3] = __hadd2(aB[3], uh(vB.w));
        }
#pragma unroll
        for (int j = 0; j < 4; j++) {
            aA[j] = h2rx(h2rx(h2rx(aA[j], 8), 16), 32);
            aB[j] = h2rx(h2rx(h2rx(aB[j], 8), 16), 32);
        }
        if (g == 0) {
            const float* p0 = x0 + (size_t)n * DD + q * 8;
            const float* p1 = h1 + (size_t)n * DD + q * 8;
            float4 v0a = *(const float4*)(p0), v0b = *(const float4*)(p0 + 4);
            float4 v1a = *(const float4*)(p1), v1b = *(const float4*)(p1 + 4);
            float o[8];
#pragma unroll
            for (int j = 0; j < 4; j++) {
                float2 fA = __half22float2(aA[j]);
                float2 fB = __half22float2(aB[j]);
                float h2x = fA.x > 0.f ? fA.x : 0.01f * fA.x;
                float h2y = fA.y > 0.f ? fA.y : 0.01f * fA.y;
                o[2 * j] = h2x + fB.x;
                o[2 * j + 1] = h2y + fB.y;
            }
            float* ob = out + (size_t)n * 256 + q * 8;
            *(float4*)(ob) = make_float4(o[0] + v0a.x + v1a.x, o[1] + v0a.y + v1a.y,
                                         o[2] + v0a.z + v1a.z, o[3] + v0a.w + v1a.w);
            *(float4*)(ob + 4) = make_float4(o[4] + v0b.x + v1b.x, o[5] + v0b.y + v1b.y,
                                             o[6] + v0b.z + v1b.z, o[7] + v0b.w + v1b.w);
        }
    }
}

extern "C" void kernel_launch(void* const* d_in, const int* in_sizes, int n_in,
                              void* d_out, int out_size, void* d_ws, size_t ws_size,
                              hipStream_t stream) {
    const int* ei       = (const int*)d_in[0];
    const float* v_feat = (const float*)d_in[1];
    const float* a_feat = (const float*)d_in[2];
    const float* t_feat = (const float*)d_in[3];
    const float* pref_v = (const float*)d_in[4];
    const float* pref_a = (const float*)d_in[5];
    const float* pref_t = (const float*)d_in[6];
    const float* mlp_v_w = (const float*)d_in[7];
    const float* mlp_v_b = (const float*)d_in[8];
    const float* mlp_a_w = (const float*)d_in[9];
    const float* mlp_a_b = (const float*)d_in[10];
    const float* mlp_t_w = (const float*)d_in[11];
    const float* mlp_t_b = (const float*)d_in[12];
    const float* pre_w  = (const float*)d_in[13];
    const float* ori_w  = (const float*)d_in[14];
    const float* gcn_w  = (const float*)d_in[15];
    const float* id_emb = (const float*)d_in[16];
    float* out = (float*)d_out;

    const int E2 = in_sizes[0];
    const int E  = E2 / 2;

    char* w = (char*)d_ws;
    auto alloc = [&](size_t bytes) -> void* {
        void* p = (void*)w;
        w += (bytes + 255) & ~(size_t)255;
        return p;
    };
    int* cnt  = (int*)alloc((size_t)NN * 4);
    int* rp   = (int*)alloc((size_t)(NN + 1) * 4);
    int* bsum = (int*)alloc(256);
    int* col  = (int*)alloc((size_t)E2 * 4);
    int* posw = (int*)alloc((size_t)E2 * 4);
    __half* Mh3  = (__half*)alloc(3 * PLANE * 2);
    __half* hb3h = (__half*)alloc(3 * PLANE * 2);
    __half* x3h  = (__half*)alloc(3 * PLANE * 2);
    float* x0f = (float*)alloc(PLANE * 4);
    float* h1f = (float*)alloc(PLANE * 4);

    __half* g1 = hb3h;
    __half* gpair = hb3h + PLANE;

    // ---- CSR by destination ----
    const int NBLK = 64, CHUNK = (NN + NBLK - 1) / NBLK;
    hipMemsetAsync(cnt, 0, (size_t)NN * 4, stream);
    k_hist<<<(E2 + 255) / 256, 256, 0, stream>>>(ei, E2, E, cnt, posw);
    k_bsum<<<NBLK, 256, 0, stream>>>(cnt, bsum, NN, CHUNK);
    k_bscan<<<1, 64, 0, stream>>>(bsum, NBLK, rp + NN);
    k_apply<<<NBLK, 256, 0, stream>>>(cnt, bsum, rp, NN, CHUNK);
    k_scatter<<<(E2 + 255) / 256, 256, 0, stream>>>(ei, E2, E, rp, posw, col);

    // ---- node tables (interleaved fp16) ----
    k_prep_pref<<<640, 256, 0, stream>>>(pref_v, pref_a, pref_t, Mh3);
    k_mlp<128><<<1024, 256, 0, stream>>>(v_feat, mlp_v_w, mlp_v_b, Mh3, 0);
    k_mlp<128><<<1024, 256, 0, stream>>>(a_feat, mlp_a_w, mlp_a_b, Mh3, 1);
    k_mlp<100><<<1024, 256, 0, stream>>>(t_feat, mlp_t_w, mlp_t_b, Mh3, 2);

    const int GB = (NN + 3) / 4;  // one wave per node

    // ---- 3-modality chains (gates fused into gat_pre) ----
    dim3 gm(640, 3);
    k_gemm_mfma<<<gm, 256, 0, stream>>>(Mh3, pre_w, hb3h);
    k_gat_pre3<<<GB, 256, 0, stream>>>(Mh3, hb3h, rp, col, x3h);
    for (int it = 0; it < 3; it++) {
        k_gemm_mfma<<<gm, 256, 0, stream>>>(x3h, ori_w, hb3h);
        if (it < 2)
            k_gat_ori3<<<GB, 256, 0, stream>>>(hb3h, x3h, rp, col, x3h, nullptr);
        else
            k_gat_ori3<<<GB, 256, 0, stream>>>(hb3h, x3h, rp, col, nullptr, out);
    }

    // ---- real_gcn ----
    k_gemm_id<<<1280, 256, 0, stream>>>(id_emb, gcn_w, g1, x0f);
    k_gcn1<<<GB, 256, 0, stream>>>(g1, rp, col, h1f);
    dim3 g2(1280, 2);
    k_gemm_f2<<<g2, 256, 0, stream>>>(h1f, gcn_w + 4096, gpair);
    k_gcn_final2<<<GB, 256, 0, stream>>>(gpair, rp, col, x0f, h1f, out);
}

// Round 12
// 546.458 us; speedup vs baseline: 1.2205x; 1.0172x over previous
//
#include <hip/hip_runtime.h>
#include <hip/hip_fp16.h>
#include <math.h>

#define NUSER 10000
#define NITEM 30000
#define NN    40000
#define DD    64
#define PLANE ((size_t)NN * DD)

typedef _Float16 hv2 __attribute__((ext_vector_type(2)));
typedef _Float16 half8v __attribute__((ext_vector_type(8)));
typedef float float4v __attribute__((ext_vector_type(4)));
union U2H { unsigned u; hv2 v; __half2 hh; };

#if defined(__has_builtin)
#if __has_builtin(__builtin_amdgcn_fdot2)
#define HAS_FDOT2 1
#endif
#endif

__device__ __forceinline__ float fdot2u(unsigned a, unsigned b, float c) {
#ifdef HAS_FDOT2
    U2H x, y;
    x.u = a;
    y.u = b;
    return __builtin_amdgcn_fdot2(x.v, y.v, c, false);
#else
    U2H x, y;
    x.u = a;
    y.u = b;
    float2 fa = __half22float2(x.hh), fb = __half22float2(y.hh);
    return c + fa.x * fb.x + fa.y * fb.y;
#endif
}

__device__ __forceinline__ float dot8(uint4 a, uint4 b) {
    float d = fdot2u(a.x, b.x, 0.f);
    d = fdot2u(a.y, b.y, d);
    d = fdot2u(a.z, b.z, d);
    d = fdot2u(a.w, b.w, d);
    return d;
}

__device__ __forceinline__ __half2 uh(unsigned u) { U2H x; x.u = u; return x.hh; }
__device__ __forceinline__ unsigned hu(__half2 h) { U2H x; x.hh = h; return x.u; }
__device__ __forceinline__ __half2 h2rx(__half2 v, int m) {
    return __hadd2(v, uh((unsigned)__shfl_xor((int)hu(v), m, 64)));
}

__device__ __forceinline__ float wsum(float v) {
#pragma unroll
    for (int o = 32; o > 0; o >>= 1) v += __shfl_xor(v, o, 64);
    return v;
}
__device__ __forceinline__ float qsum8(float v) {
    v += __shfl_xor(v, 1, 64);
    v += __shfl_xor(v, 2, 64);
    v += __shfl_xor(v, 4, 64);
    return v;
}
__device__ __forceinline__ float gsum8f(float v) {
    v += __shfl_xor(v, 8, 64);
    v += __shfl_xor(v, 16, 64);
    v += __shfl_xor(v, 32, 64);
    return v;
}

// item-first node order: item-dst edges gather the 3.84MB user slice (L2-resident),
// user-dst edges gather the item slice. Phases separate naturally with block order.
__device__ __forceinline__ int orderIF(int i) {
    return (i < NITEM) ? (NUSER + i) : (i - NITEM);
}

// ---------------- CSR build ----------------
__global__ void k_hist(const int* ei, int E2, int E, int* cnt, int* posw) {
    int i = blockIdx.x * blockDim.x + threadIdx.x;
    if (i >= E2) return;
    int d = (i < E) ? ei[E + i] : ei[i - E];
    posw[i] = atomicAdd(&cnt[d], 1);
}

__global__ void k_bsum(const int* __restrict__ cnt, int* __restrict__ bsum, int n, int chunk) {
    __shared__ int wsh[4];
    int b = blockIdx.x, tid = threadIdx.x;
    int base = b * chunk, end = min(n, base + chunk);
    int s = 0;
    for (int i = base + tid; i < end; i += 256) s += cnt[i];
#pragma unroll
    for (int o = 32; o > 0; o >>= 1) s += __shfl_xor(s, o, 64);
    if ((tid & 63) == 0) wsh[tid >> 6] = s;
    __syncthreads();
    if (tid == 0) bsum[b] = wsh[0] + wsh[1] + wsh[2] + wsh[3];
}

__global__ void k_bscan(int* bsum, int nb, int* rp_end) {
    int lane = threadIdx.x;
    int v = (lane < nb) ? bsum[lane] : 0;
    int orig = v;
#pragma unroll
    for (int o = 1; o < 64; o <<= 1) {
        int y = __shfl_up(v, o, 64);
        if (lane >= o) v += y;
    }
    if (lane < nb) bsum[lane] = v - orig;
    if (lane == 63) *rp_end = v;
}

__global__ void k_apply(const int* __restrict__ cnt, const int* __restrict__ boff,
                        int* __restrict__ rp, int n, int chunk) {
    __shared__ int buf[256];
    __shared__ int csh;
    int b = blockIdx.x, tid = threadIdx.x;
    int base = b * chunk, end = min(n, base + chunk);
    int carry = boff[b];
    for (int t0 = base; t0 < end; t0 += 256) {
        int i = t0 + tid;
        int v = (i < end) ? cnt[i] : 0;
        int x = v;
        buf[tid] = x;
        __syncthreads();
        for (int o = 1; o < 256; o <<= 1) {
            int y = (tid >= o) ? buf[tid - o] : 0;
            __syncthreads();
            x += y;
            buf[tid] = x;
            __syncthreads();
        }
        if (i < end) rp[i] = carry + x - v;
        __syncthreads();
        if (tid == 255) csh = carry + x;
        __syncthreads();
        carry = csh;
    }
}

__global__ void k_scatter(const int* ei, int E2, int E, const int* rp,
                          const int* __restrict__ posw, int* col) {
    int i = blockIdx.x * blockDim.x + threadIdx.x;
    if (i >= E2) return;
    int j = (i < E) ? i : i - E;
    int s = (i < E) ? ei[j] : ei[E + j];
    int d = (i < E) ? ei[E + j] : ei[j];
    col[rp[d] + posw[i]] = s;
}

// ---------------- node prep: 3 prefs -> interleaved fp16 M ----------------
__global__ void k_prep_pref(const float* __restrict__ pv, const float* __restrict__ pa,
                            const float* __restrict__ pt, __half* __restrict__ M) {
    int t = blockIdx.x * blockDim.x + threadIdx.x;
    int w = t >> 6, lane = t & 63, nw = (gridDim.x * blockDim.x) >> 6;
    for (int r = w; r < NUSER; r += nw) {
        float a = pv[(size_t)r * DD + lane];
        float b = pa[(size_t)r * DD + lane];
        float c = pt[(size_t)r * DD + lane];
        float sa = a * a, sb = b * b, sc = c * c;
#pragma unroll
        for (int o = 32; o > 0; o >>= 1) {
            sa += __shfl_xor(sa, o, 64);
            sb += __shfl_xor(sb, o, 64);
            sc += __shfl_xor(sc, o, 64);
        }
        size_t base = (size_t)r * 3 * DD + lane;
        M[base] = __float2half(a / fmaxf(sqrtf(sa), 1e-12f));
        M[base + DD] = __float2half(b / fmaxf(sqrtf(sb), 1e-12f));
        M[base + 2 * DD] = __float2half(c / fmaxf(sqrtf(sc), 1e-12f));
    }
}

template <int K>
__global__ void k_mlp(const float* __restrict__ feat, const float* __restrict__ W,
                      const float* __restrict__ bias, __half* __restrict__ M, int mo) {
    constexpr int K4 = K / 4;
    __shared__ float4 Wl[K4][DD];
    __shared__ float4 rbuf[4][2][K4];
    int t = threadIdx.x, wib = t >> 6, lane = t & 63;
    for (int i = t; i < DD * K4; i += 256) {
        int c = i / K4, k4 = i - c * K4;
        Wl[k4][c] = *(const float4*)(W + (size_t)c * K + k4 * 4);
    }
    __syncthreads();
    float b = bias[lane];
    const int stride = gridDim.x * 4;
    int r = blockIdx.x * 4 + wib;
    float4 v = {0.f, 0.f, 0.f, 0.f};
    if (r < NITEM && lane < K4) v = *(const float4*)(feat + (size_t)r * K + lane * 4);
    int cur = 0;
    for (; r < NITEM; r += stride) {
        if (lane < K4) rbuf[wib][cur][lane] = v;
        int rn = r + stride;
        if (rn < NITEM && lane < K4) v = *(const float4*)(feat + (size_t)rn * K + lane * 4);
        asm volatile("s_waitcnt lgkmcnt(0)" ::: "memory");
        float acc = b;
#pragma unroll
        for (int k4 = 0; k4 < K4; k4++) {
            float4 x4 = rbuf[wib][cur][k4];
            float4 w4 = Wl[k4][lane];
            acc += x4.x * w4.x + x4.y * w4.y + x4.z * w4.z + x4.w * w4.w;
        }
        float h = acc > 0.f ? acc : 0.01f * acc;
        float n = sqrtf(wsum(h * h));
        M[((size_t)(NUSER + r) * 3 + mo) * DD + lane] = __float2half(h / fmaxf(n, 1e-12f));
        cur ^= 1;
    }
}

// ---------------- MFMA GEMM: fp16 interleaved-3 in/out ----------------
__global__ void k_gemm_mfma(const __half* __restrict__ x3, const float* __restrict__ W3,
                            __half* __restrict__ o3) {
    int mo = blockIdx.y;
    const float* W = W3 + (size_t)mo * 4096;
    int t = threadIdx.x, wv = t >> 6, lane = t & 63;
    int lr = lane & 15, lg = lane >> 4;
    half8v b[4][2];
#pragma unroll
    for (int ct = 0; ct < 4; ct++)
#pragma unroll
        for (int kh = 0; kh < 2; kh++)
#pragma unroll
            for (int i = 0; i < 8; i++)
                b[ct][kh][i] = (_Float16)W[(kh * 32 + lg * 8 + i) * 64 + ct * 16 + lr];
    const int NT = NN / 16;
    for (int rt = blockIdx.x * 4 + wv; rt < NT; rt += gridDim.x * 4) {
        const __half* xr = x3 + ((size_t)(rt * 16 + lr) * 3 + mo) * DD + lg * 8;
        half8v a0 = *(const half8v*)xr;
        half8v a1 = *(const half8v*)(xr + 32);
        float4v acc0 = {0.f, 0.f, 0.f, 0.f}, acc1 = acc0, acc2 = acc0, acc3 = acc0;
        acc0 = __builtin_amdgcn_mfma_f32_16x16x32_f16(a0, b[0][0], acc0, 0, 0, 0);
        acc1 = __builtin_amdgcn_mfma_f32_16x16x32_f16(a0, b[1][0], acc1, 0, 0, 0);
        acc2 = __builtin_amdgcn_mfma_f32_16x16x32_f16(a0, b[2][0], acc2, 0, 0, 0);
        acc3 = __builtin_amdgcn_mfma_f32_16x16x32_f16(a0, b[3][0], acc3, 0, 0, 0);
        acc0 = __builtin_amdgcn_mfma_f32_16x16x32_f16(a1, b[0][1], acc0, 0, 0, 0);
        acc1 = __builtin_amdgcn_mfma_f32_16x16x32_f16(a1, b[1][1], acc1, 0, 0, 0);
        acc2 = __builtin_amdgcn_mfma_f32_16x16x32_f16(a1, b[2][1], acc2, 0, 0, 0);
        acc3 = __builtin_amdgcn_mfma_f32_16x16x32_f16(a1, b[3][1], acc3, 0, 0, 0);
#pragma unroll
        for (int i = 0; i < 4; i++) {
            size_t rbase = ((size_t)(rt * 16 + lg * 4 + i) * 3 + mo) * DD + lr;
            o3[rbase] = __float2half(acc0[i]);
            o3[rbase + 16] = __float2half(acc1[i]);
            o3[rbase + 32] = __float2half(acc2[i]);
            o3[rbase + 48] = __float2half(acc3[i]);
        }
    }
}

__global__ void k_gemm_f2(const float* __restrict__ x, const float* __restrict__ W2,
                          __half* __restrict__ o2) {
    __shared__ float rowbuf[4][DD];
    int mo = blockIdx.y;
    const float* W = W2 + (size_t)mo * 4096;
    int t = threadIdx.x, wib = t >> 6, lane = t & 63;
    float Wc[DD];
#pragma unroll
    for (int k = 0; k < DD; k++) Wc[k] = W[k * DD + lane];
    for (int r = blockIdx.x * 4 + wib; r < NN; r += gridDim.x * 4) {
        rowbuf[wib][lane] = x[(size_t)r * DD + lane];
        asm volatile("s_waitcnt lgkmcnt(0)" ::: "memory");
        float acc = 0.f;
#pragma unroll
        for (int k4 = 0; k4 < DD / 4; k4++) {
            float4 xq = *(const float4*)&rowbuf[wib][k4 * 4];
            acc += xq.x * Wc[k4 * 4] + xq.y * Wc[k4 * 4 + 1] + xq.z * Wc[k4 * 4 + 2] +
                   xq.w * Wc[k4 * 4 + 3];
        }
        o2[((size_t)r * 2 + mo) * DD + lane] = __float2half(acc);
    }
}

__global__ void k_gemm_id(const float* __restrict__ x, const float* __restrict__ W,
                          __half* __restrict__ hout, float* __restrict__ xnorm) {
    __shared__ float rowbuf[4][DD];
    int t = threadIdx.x, wib = t >> 6, lane = t & 63;
    float Wc[DD];
#pragma unroll
    for (int k = 0; k < DD; k++) Wc[k] = W[k * DD + lane];
    for (int r = blockIdx.x * 4 + wib; r < NN; r += gridDim.x * 4) {
        float xv = x[(size_t)r * DD + lane];
        float n = sqrtf(wsum(xv * xv));
        xv /= fmaxf(n, 1e-12f);
        xnorm[(size_t)r * DD + lane] = xv;
        rowbuf[wib][lane] = xv;
        asm volatile("s_waitcnt lgkmcnt(0)" ::: "memory");
        float acc = 0.f;
#pragma unroll
        for (int k4 = 0; k4 < DD / 4; k4++) {
            float4 xq = *(const float4*)&rowbuf[wib][k4 * 4];
            acc += xq.x * Wc[k4 * 4] + xq.y * Wc[k4 * 4 + 1] + xq.z * Wc[k4 * 4 + 2] +
                   xq.w * Wc[k4 * 4 + 3];
        }
        hout[(size_t)r * DD + lane] = __float2half(acc);
    }
}

// ---------------- fused GAT pre + inline cross-modal gates ----------------
__device__ __forceinline__ float gatef(float ssum) {
    float gate = 1.f / (1.f + __expf(-0.5f * ssum));
    return gate > 0.5f ? gate : 1.f;
}

__global__ void k_gat_pre3(const __half* __restrict__ M, const __half* __restrict__ h3,
                           const int* __restrict__ rp, const int* __restrict__ col,
                           __half* __restrict__ x3h) {
    int t = blockIdx.x * blockDim.x + threadIdx.x;
    int wv = t >> 6, lane = t & 63, nw = (gridDim.x * blockDim.x) >> 6;
    int g = lane >> 3, q = lane & 7;
    const __half2 z = __floats2half2_rn(0.f, 0.f);
    for (int w0 = wv; w0 < NN; w0 += nw) {
        int n = orderIF(w0);
        int e0 = rp[n], e1 = rp[n + 1];
        const uint4* mrow = (const uint4*)(M + (size_t)n * 192);
        uint4 tv = mrow[q], ta = mrow[q + 8], tt = mrow[q + 16];
        const uint4* hrow = (const uint4*)(h3 + (size_t)n * 192);
        uint4 hd0 = hrow[q], hd1 = hrow[q + 8], hd2 = hrow[q + 16];
        float s0 = 0.f, s1 = 0.f, s2 = 0.f;
        __half2 a0[4] = {z, z, z, z}, a1[4] = {z, z, z, z}, a2[4] = {z, z, z, z};
        for (int eb = e0 + g; eb < e1; eb += 8) {
            int sn = col[eb];
            const uint4* srow = (const uint4*)(M + (size_t)sn * 192);
            uint4 sv = srow[q], sa = srow[q + 8], st = srow[q + 16];
            float dv = qsum8(dot8(tv, sv));
            float da = qsum8(dot8(ta, sa));
            float dt = qsum8(dot8(tt, st));
            float ga = gatef(da + dt), gb_ = gatef(dv + dt), gc = gatef(da + dv);
            const uint4* hsrow = (const uint4*)(h3 + (size_t)sn * 192);
            uint4 v0 = hsrow[q], v1 = hsrow[q + 8], v2 = hsrow[q + 16];
            float d0 = qsum8(dot8(hd0, v0));
            float d1 = qsum8(dot8(hd1, v1));
            float d2 = qsum8(dot8(hd2, v2));
            float sc0 = d0 > 0.f ? d0 : 0.2f * d0;
            float sc1 = d1 > 0.f ? d1 : 0.2f * d1;
            float sc2 = d2 > 0.f ? d2 : 0.2f * d2;
            float p0 = __expf(sc0), p1 = __expf(sc1), p2 = __expf(sc2);
            s0 += p0;
            s1 += p1;
            s2 += p2;
            __half2 ph0 = __float2half2_rn(p0 * ga);
            __half2 ph1 = __float2half2_rn(p1 * gb_);
            __half2 ph2 = __float2half2_rn(p2 * gc);
            a0[0] = __hfma2(ph0, uh(v0.x), a0[0]);
            a0[1] = __hfma2(ph0, uh(v0.y), a0[1]);
            a0[2] = __hfma2(ph0, uh(v0.z), a0[2]);
            a0[3] = __hfma2(ph0, uh(v0.w), a0[3]);
            a1[0] = __hfma2(ph1, uh(v1.x), a1[0]);
            a1[1] = __hfma2(ph1, uh(v1.y), a1[1]);
            a1[2] = __hfma2(ph1, uh(v1.z), a1[2]);
            a1[3] = __hfma2(ph1, uh(v1.w), a1[3]);
            a2[0] = __hfma2(ph2, uh(v2.x), a2[0]);
            a2[1] = __hfma2(ph2, uh(v2.y), a2[1]);
            a2[2] = __hfma2(ph2, uh(v2.z), a2[2]);
            a2[3] = __hfma2(ph2, uh(v2.w), a2[3]);
        }
        s0 = gsum8f(s0);
        s1 = gsum8f(s1);
        s2 = gsum8f(s2);
#pragma unroll
        for (int j = 0; j < 4; j++) {
            a0[j] = h2rx(h2rx(h2rx(a0[j], 8), 16), 32);
            a1[j] = h2rx(h2rx(h2rx(a1[j], 8), 16), 32);
            a2[j] = h2rx(h2rx(h2rx(a2[j], 8), 16), 32);
        }
        float i0 = 1.f / (s0 + 1e-16f), i1 = 1.f / (s1 + 1e-16f), i2 = 1.f / (s2 + 1e-16f);
        float o0[8], o1[8], o2[8];
#pragma unroll
        for (int j = 0; j < 4; j++) {
            float2 f0 = __half22float2(a0[j]);
            float2 f1 = __half22float2(a1[j]);
            float2 f2 = __half22float2(a2[j]);
            o0[2 * j] = f0.x * i0;
            o0[2 * j + 1] = f0.y * i0;
            o1[2 * j] = f1.x * i1;
            o1[2 * j + 1] = f1.y * i1;
            o2[2 * j] = f2.x * i2;
            o2[2 * j + 1] = f2.y * i2;
        }
        float n0 = 0.f, n1 = 0.f, n2 = 0.f;
#pragma unroll
        for (int k = 0; k < 8; k++) {
            n0 += o0[k] * o0[k];
            n1 += o1[k] * o1[k];
            n2 += o2[k] * o2[k];
        }
        n0 = qsum8(n0);
        n1 = qsum8(n1);
        n2 = qsum8(n2);
        float r0 = 1.f / fmaxf(sqrtf(n0), 1e-12f);
        float r1 = 1.f / fmaxf(sqrtf(n1), 1e-12f);
        float r2 = 1.f / fmaxf(sqrtf(n2), 1e-12f);
        if (g == 0) {
            uint4* orow = (uint4*)(x3h + (size_t)n * 192);
            uint4 w0_, w1_, w2_;
            w0_.x = hu(__floats2half2_rn(o0[0] * r0, o0[1] * r0));
            w0_.y = hu(__floats2half2_rn(o0[2] * r0, o0[3] * r0));
            w0_.z = hu(__floats2half2_rn(o0[4] * r0, o0[5] * r0));
            w0_.w = hu(__floats2half2_rn(o0[6] * r0, o0[7] * r0));
            w1_.x = hu(__floats2half2_rn(o1[0] * r1, o1[1] * r1));
            w1_.y = hu(__floats2half2_rn(o1[2] * r1, o1[3] * r1));
            w1_.z = hu(__floats2half2_rn(o1[4] * r1, o1[5] * r1));
            w1_.w = hu(__floats2half2_rn(o1[6] * r1, o1[7] * r1));
            w2_.x = hu(__floats2half2_rn(o2[0] * r2, o2[1] * r2));
            w2_.y = hu(__floats2half2_rn(o2[2] * r2, o2[3] * r2));
            w2_.z = hu(__floats2half2_rn(o2[4] * r2, o2[5] * r2));
            w2_.w = hu(__floats2half2_rn(o2[6] * r2, o2[7] * r2));
            orow[q] = w0_;
            orow[q + 8] = w1_;
            orow[q + 16] = w2_;
        }
    }
}

// ---------------- fused 3-modality GAT ori (residual + l2norm) ----------------
__global__ void k_gat_ori3(const __half* __restrict__ h3, const __half* __restrict__ x3h,
                           const int* __restrict__ rp, const int* __restrict__ col,
                           __half* __restrict__ xout, float* __restrict__ fout) {
    int t = blockIdx.x * blockDim.x + threadIdx.x;
    int wv = t >> 6, lane = t & 63, nw = (gridDim.x * blockDim.x) >> 6;
    int g = lane >> 3, q = lane & 7;
    const __half2 z = __floats2half2_rn(0.f, 0.f);
    for (int w0 = wv; w0 < NN; w0 += nw) {
        int n = orderIF(w0);
        int e0 = rp[n], e1 = rp[n + 1];
        const uint4* hrow = (const uint4*)(h3 + (size_t)n * 192);
        uint4 hd0 = hrow[q], hd1 = hrow[q + 8], hd2 = hrow[q + 16];
        float s0 = 0.f, s1 = 0.f, s2 = 0.f;
        __half2 a0[4] = {z, z, z, z}, a1[4] = {z, z, z, z}, a2[4] = {z, z, z, z};
        for (int eb = e0 + g; eb < e1; eb += 8) {
            int sn = col[eb];
            const uint4* srow = (const uint4*)(h3 + (size_t)sn * 192);
            uint4 v0 = srow[q], v1 = srow[q + 8], v2 = srow[q + 16];
            float d0 = qsum8(dot8(hd0, v0));
            float d1 = qsum8(dot8(hd1, v1));
            float d2 = qsum8(dot8(hd2, v2));
            float sc0 = d0 > 0.f ? d0 : 0.2f * d0;
            float sc1 = d1 > 0.f ? d1 : 0.2f * d1;
            float sc2 = d2 > 0.f ? d2 : 0.2f * d2;
            float p0 = __expf(sc0), p1 = __expf(sc1), p2 = __expf(sc2);
            s0 += p0;
            s1 += p1;
            s2 += p2;
            __half2 ph0 = __float2half2_rn(p0);
            __half2 ph1 = __float2half2_rn(p1);
            __half2 ph2 = __float2half2_rn(p2);
            a0[0] = __hfma2(ph0, uh(v0.x), a0[0]);
            a0[1] = __hfma2(ph0, uh(v0.y), a0[1]);
            a0[2] = __hfma2(ph0, uh(v0.z), a0[2]);
            a0[3] = __hfma2(ph0, uh(v0.w), a0[3]);
            a1[0] = __hfma2(ph1, uh(v1.x), a1[0]);
            a1[1] = __hfma2(ph1, uh(v1.y), a1[1]);
            a1[2] = __hfma2(ph1, uh(v1.z), a1[2]);
            a1[3] = __hfma2(ph1, uh(v1.w), a1[3]);
            a2[0] = __hfma2(ph2, uh(v2.x), a2[0]);
            a2[1] = __hfma2(ph2, uh(v2.y), a2[1]);
            a2[2] = __hfma2(ph2, uh(v2.z), a2[2]);
            a2[3] = __hfma2(ph2, uh(v2.w), a2[3]);
        }
        s0 = gsum8f(s0);
        s1 = gsum8f(s1);
        s2 = gsum8f(s2);
#pragma unroll
        for (int j = 0; j < 4; j++) {
            a0[j] = h2rx(h2rx(h2rx(a0[j], 8), 16), 32);
            a1[j] = h2rx(h2rx(h2rx(a1[j], 8), 16), 32);
            a2[j] = h2rx(h2rx(h2rx(a2[j], 8), 16), 32);
        }
        float i0 = 1.f / (s0 + 1e-16f), i1 = 1.f / (s1 + 1e-16f), i2 = 1.f / (s2 + 1e-16f);
        const uint4* xrow = (const uint4*)(x3h + (size_t)n * 192);
        uint4 xr0 = xrow[q], xr1 = xrow[q + 8], xr2 = xrow[q + 16];
        float o0[8], o1[8], o2[8];
#pragma unroll
        for (int j = 0; j < 4; j++) {
            float2 f0 = __half22float2(a0[j]);
            float2 f1 = __half22float2(a1[j]);
            float2 f2 = __half22float2(a2[j]);
            float2 xf0 = __half22float2(uh(j == 0 ? xr0.x : j == 1 ? xr0.y : j == 2 ? xr0.z : xr0.w));
            float2 xf1 = __half22float2(uh(j == 0 ? xr1.x : j == 1 ? xr1.y : j == 2 ? xr1.z : xr1.w));
            float2 xf2 = __half22float2(uh(j == 0 ? xr2.x : j == 1 ? xr2.y : j == 2 ? xr2.z : xr2.w));
            o0[2 * j] = xf0.x + f0.x * i0;
            o0[2 * j + 1] = xf0.y + f0.y * i0;
            o1[2 * j] = xf1.x + f1.x * i1;
            o1[2 * j + 1] = xf1.y + f1.y * i1;
            o2[2 * j] = xf2.x + f2.x * i2;
            o2[2 * j + 1] = xf2.y + f2.y * i2;
        }
        float n0 = 0.f, n1 = 0.f, n2 = 0.f;
#pragma unroll
        for (int k = 0; k < 8; k++) {
            n0 += o0[k] * o0[k];
            n1 += o1[k] * o1[k];
            n2 += o2[k] * o2[k];
        }
        n0 = qsum8(n0);
        n1 = qsum8(n1);
        n2 = qsum8(n2);
        float r0 = 1.f / fmaxf(sqrtf(n0), 1e-12f);
        float r1 = 1.f / fmaxf(sqrtf(n1), 1e-12f);
        float r2 = 1.f / fmaxf(sqrtf(n2), 1e-12f);
        if (g == 0) {
            if (fout) {
                float* ob = fout + (size_t)n * 256 + 64 + q * 8;
                *(float4*)(ob) = make_float4(o0[0] * r0, o0[1] * r0, o0[2] * r0, o0[3] * r0);
                *(float4*)(ob + 4) = make_float4(o0[4] * r0, o0[5] * r0, o0[6] * r0, o0[7] * r0);
                *(float4*)(ob + 64) = make_float4(o1[0] * r1, o1[1] * r1, o1[2] * r1, o1[3] * r1);
                *(float4*)(ob + 68) = make_float4(o1[4] * r1, o1[5] * r1, o1[6] * r1, o1[7] * r1);
                *(float4*)(ob + 128) = make_float4(o2[0] * r2, o2[1] * r2, o2[2] * r2, o2[3] * r2);
                *(float4*)(ob + 132) = make_float4(o2[4] * r2, o2[5] * r2, o2[6] * r2, o2[7] * r2);
            } else {
                uint4* orow = (uint4*)(xout + (size_t)n * 192);
                uint4 w0_, w1_, w2_;
                w0_.x = hu(__floats2half2_rn(o0[0] * r0, o0[1] * r0));
                w0_.y = hu(__floats2half2_rn(o0[2] * r0, o0[3] * r0));
                w0_.z = hu(__floats2half2_rn(o0[4] * r0, o0[5] * r0));
                w0_.w = hu(__floats2half2_rn(o0[6] * r0, o0[7] * r0));
                w1_.x = hu(__floats2half2_rn(o1[0] * r1, o1[1] * r1));
                w1_.y = hu(__floats2half2_rn(o1[2] * r1, o1[3] * r1));
                w1_.z = hu(__floats2half2_rn(o1[4] * r1, o1[5] * r1));
                w1_.w = hu(__floats2half2_rn(o1[6] * r1, o1[7] * r1));
                w2_.x = hu(__floats2half2_rn(o2[0] * r2, o2[1] * r2));
                w2_.y = hu(__floats2half2_rn(o2[2] * r2, o2[3] * r2));
                w2_.z = hu(__floats2half2_rn(o2[4] * r2, o2[5] * r2));
                w2_.w = hu(__floats2half2_rn(o2[6] * r2, o2[7] * r2));
                orow[q] = w0_;
                orow[q + 8] = w1_;
                orow[q + 16] = w2_;
            }
        }
    }
}

// ---------------- GCN ----------------
__global__ void k_gcn1(const __half* __restrict__ h, const int* __restrict__ rp,
                       const int* __restrict__ col, float* __restrict__ out) {
    int t = blockIdx.x * blockDim.x + threadIdx.x;
    int wv = t >> 6, lane = t & 63, nw = (gridDim.x * blockDim.x) >> 6;
    int g = lane >> 3, q = lane & 7;
    const __half2 z = __floats2half2_rn(0.f, 0.f);
    for (int w0 = wv; w0 < NN; w0 += nw) {
        int n = orderIF(w0);
        int e0 = rp[n], e1 = rp[n + 1];
        __half2 a[4] = {z, z, z, z};
        for (int eb = e0 + g; eb < e1; eb += 8) {
            int sn = col[eb];
            uint4 v = ((const uint4*)(h + (size_t)sn * DD))[q];
            a[0] = __hadd2(a[0], uh(v.x));
            a[1] = __hadd2(a[1], uh(v.y));
            a[2] = __hadd2(a[2], uh(v.z));
            a[3] = __hadd2(a[3], uh(v.w));
        }
#pragma unroll
        for (int j = 0; j < 4; j++) a[j] = h2rx(h2rx(h2rx(a[j], 8), 16), 32);
        if (g == 0) {
            float o[8];
#pragma unroll
            for (int j = 0; j < 4; j++) {
                float2 f = __half22float2(a[j]);
                o[2 * j] = f.x > 0.f ? f.x : 0.01f * f.x;
                o[2 * j + 1] = f.y > 0.f ? f.y : 0.01f * f.y;
            }
            float* ob = out + (size_t)n * DD + q * 8;
            *(float4*)(ob) = make_float4(o[0], o[1], o[2], o[3]);
            *(float4*)(ob + 4) = make_float4(o[4], o[5], o[6], o[7]);
        }
    }
}

__global__ void k_gcn_final2(const __half* __restrict__ gp, const int* __restrict__ rp,
                             const int* __restrict__ col, const float* __restrict__ x0,
                             const float* __restrict__ h1, float* __restrict__ out) {
    int t = blockIdx.x * blockDim.x + threadIdx.x;
    int wv = t >> 6, lane = t & 63, nw = (gridDim.x * blockDim.x) >> 6;
    int g = lane >> 3, q = lane & 7;
    const __half2 z = __floats2half2_rn(0.f, 0.f);
    for (int w0 = wv; w0 < NN; w0 += nw) {
        int n = orderIF(w0);
        int e0 = rp[n], e1 = rp[n + 1];
        __half2 aA[4] = {z, z, z, z}, aB[4] = {z, z, z, z};
        for (int eb = e0 + g; eb < e1; eb += 8) {
            int sn = col[eb];
            const uint4* base = (const uint4*)(gp + (size_t)sn * 128);
            uint4 vA = base[q], vB = base[q + 8];
            aA[0] = __hadd2(aA[0], uh(vA.x));
            aA[1] = __hadd2(aA[1], uh(vA.y));
            aA[2] = __hadd2(aA[2], uh(vA.z));
            aA[3] = __hadd2(aA[3], uh(vA.w));
            aB[0] = __hadd2(aB[0], uh(vB.x));
            aB[1] = __hadd2(aB[1], uh(vB.y));
            aB[2] = __hadd2(aB[2], uh(vB.z));
            aB[3] = __hadd2(aB[3], uh(vB.w));
        }
#pragma unroll
        for (int j = 0; j < 4; j++) {
            aA[j] = h2rx(h2rx(h2rx(aA[j], 8), 16), 32);
            aB[j] = h2rx(h2rx(h2rx(aB[j], 8), 16), 32);
        }
        if (g == 0) {
            const float* p0 = x0 + (size_t)n * DD + q * 8;
            const float* p1 = h1 + (size_t)n * DD + q * 8;
            float4 v0a = *(const float4*)(p0), v0b = *(const float4*)(p0 + 4);
            float4 v1a = *(const float4*)(p1), v1b = *(const float4*)(p1 + 4);
            float o[8];
#pragma unroll
            for (int j = 0; j < 4; j++) {
                float2 fA = __half22float2(aA[j]);
                float2 fB = __half22float2(aB[j]);
                float h2x = fA.x > 0.f ? fA.x : 0.01f * fA.x;
                float h2y = fA.y > 0.f ? fA.y : 0.01f * fA.y;
                o[2 * j] = h2x + fB.x;
                o[2 * j + 1] = h2y + fB.y;
            }
            float* ob = out + (size_t)n * 256 + q * 8;
            *(float4*)(ob) = make_float4(o[0] + v0a.x + v1a.x, o[1] + v0a.y + v1a.y,
                                         o[2] + v0a.z + v1a.z, o[3] + v0a.w + v1a.w);
            *(float4*)(ob + 4) = make_float4(o[4] + v0b.x + v1b.x, o[5] + v0b.y + v1b.y,
                                             o[6] + v0b.z + v1b.z, o[7] + v0b.w + v1b.w);
        }
    }
}

extern "C" void kernel_launch(void* const* d_in, const int* in_sizes, int n_in,
                              void* d_out, int out_size, void* d_ws, size_t ws_size,
                              hipStream_t stream) {
    const int* ei       = (const int*)d_in[0];
    const float* v_feat = (const float*)d_in[1];
    const float* a_feat = (const float*)d_in[2];
    const float* t_feat = (const float*)d_in[3];
    const float* pref_v = (const float*)d_in[4];
    const float* pref_a = (const float*)d_in[5];
    const float* pref_t = (const float*)d_in[6];
    const float* mlp_v_w = (const float*)d_in[7];
    const float* mlp_v_b = (const float*)d_in[8];
    const float* mlp_a_w = (const float*)d_in[9];
    const float* mlp_a_b = (const float*)d_in[10];
    const float* mlp_t_w = (const float*)d_in[11];
    const float* mlp_t_b = (const float*)d_in[12];
    const float* pre_w  = (const float*)d_in[13];
    const float* ori_w  = (const float*)d_in[14];
    const float* gcn_w  = (const float*)d_in[15];
    const float* id_emb = (const float*)d_in[16];
    float* out = (float*)d_out;

    const int E2 = in_sizes[0];
    const int E  = E2 / 2;

    char* w = (char*)d_ws;
    auto alloc = [&](size_t bytes) -> void* {
        void* p = (void*)w;
        w += (bytes + 255) & ~(size_t)255;
        return p;
    };
    int* cnt  = (int*)alloc((size_t)NN * 4);
    int* rp   = (int*)alloc((size_t)(NN + 1) * 4);
    int* bsum = (int*)alloc(256);
    int* col  = (int*)alloc((size_t)E2 * 4);
    int* posw = (int*)alloc((size_t)E2 * 4);
    __half* Mh3  = (__half*)alloc(3 * PLANE * 2);
    __half* hb3h = (__half*)alloc(3 * PLANE * 2);
    __half* x3h  = (__half*)alloc(3 * PLANE * 2);
    float* x0f = (float*)alloc(PLANE * 4);
    float* h1f = (float*)alloc(PLANE * 4);

    __half* g1 = hb3h;
    __half* gpair = hb3h + PLANE;

    // ---- CSR by destination ----
    const int NBLK = 64, CHUNK = (NN + NBLK - 1) / NBLK;
    hipMemsetAsync(cnt, 0, (size_t)NN * 4, stream);
    k_hist<<<(E2 + 255) / 256, 256, 0, stream>>>(ei, E2, E, cnt, posw);
    k_bsum<<<NBLK, 256, 0, stream>>>(cnt, bsum, NN, CHUNK);
    k_bscan<<<1, 64, 0, stream>>>(bsum, NBLK, rp + NN);
    k_apply<<<NBLK, 256, 0, stream>>>(cnt, bsum, rp, NN, CHUNK);
    k_scatter<<<(E2 + 255) / 256, 256, 0, stream>>>(ei, E2, E, rp, posw, col);

    // ---- node tables (interleaved fp16) ----
    k_prep_pref<<<640, 256, 0, stream>>>(pref_v, pref_a, pref_t, Mh3);
    k_mlp<128><<<1024, 256, 0, stream>>>(v_feat, mlp_v_w, mlp_v_b, Mh3, 0);
    k_mlp<128><<<1024, 256, 0, stream>>>(a_feat, mlp_a_w, mlp_a_b, Mh3, 1);
    k_mlp<100><<<1024, 256, 0, stream>>>(t_feat, mlp_t_w, mlp_t_b, Mh3, 2);

    const int GB = (NN + 3) / 4;  // one wave per node

    // ---- 3-modality chains (gates fused into gat_pre) ----
    dim3 gm(640, 3);
    k_gemm_mfma<<<gm, 256, 0, stream>>>(Mh3, pre_w, hb3h);
    k_gat_pre3<<<GB, 256, 0, stream>>>(Mh3, hb3h, rp, col, x3h);
    for (int it = 0; it < 3; it++) {
        k_gemm_mfma<<<gm, 256, 0, stream>>>(x3h, ori_w, hb3h);
        if (it < 2)
            k_gat_ori3<<<GB, 256, 0, stream>>>(hb3h, x3h, rp, col, x3h, nullptr);
        else
            k_gat_ori3<<<GB, 256, 0, stream>>>(hb3h, x3h, rp, col, nullptr, out);
    }

    // ---- real_gcn ----
    k_gemm_id<<<1280, 256, 0, stream>>>(id_emb, gcn_w, g1, x0f);
    k_gcn1<<<GB, 256, 0, stream>>>(g1, rp, col, h1f);
    dim3 g2(1280, 2);
    k_gemm_f2<<<g2, 256, 0, stream>>>(h1f, gcn_w + 4096, gpair);
    k_gcn_final2<<<GB, 256, 0, stream>>>(gpair, rp, col, x0f, h1f, out);
}

// Round 13
// 542.909 us; speedup vs baseline: 1.2284x; 1.0065x over previous
//
#include <hip/hip_runtime.h>
#include <hip/hip_fp16.h>
#include <math.h>

#define NUSER 10000
#define NITEM 30000
#define NN    40000
#define DD    64
#define PLANE ((size_t)NN * DD)

typedef _Float16 hv2 __attribute__((ext_vector_type(2)));
typedef _Float16 half8v __attribute__((ext_vector_type(8)));
typedef float float4v __attribute__((ext_vector_type(4)));
union U2H { unsigned u; hv2 v; __half2 hh; };

#if defined(__has_builtin)
#if __has_builtin(__builtin_amdgcn_fdot2)
#define HAS_FDOT2 1
#endif
#endif

__device__ __forceinline__ float fdot2u(unsigned a, unsigned b, float c) {
#ifdef HAS_FDOT2
    U2H x, y;
    x.u = a;
    y.u = b;
    return __builtin_amdgcn_fdot2(x.v, y.v, c, false);
#else
    U2H x, y;
    x.u = a;
    y.u = b;
    float2 fa = __half22float2(x.hh), fb = __half22float2(y.hh);
    return c + fa.x * fb.x + fa.y * fb.y;
#endif
}

__device__ __forceinline__ float dot8(uint4 a, uint4 b) {
    float d = fdot2u(a.x, b.x, 0.f);
    d = fdot2u(a.y, b.y, d);
    d = fdot2u(a.z, b.z, d);
    d = fdot2u(a.w, b.w, d);
    return d;
}

__device__ __forceinline__ __half2 uh(unsigned u) { U2H x; x.u = u; return x.hh; }
__device__ __forceinline__ unsigned hu(__half2 h) { U2H x; x.hh = h; return x.u; }
__device__ __forceinline__ __half2 h2rx(__half2 v, int m) {
    return __hadd2(v, uh((unsigned)__shfl_xor((int)hu(v), m, 64)));
}

__device__ __forceinline__ float wsum(float v) {
#pragma unroll
    for (int o = 32; o > 0; o >>= 1) v += __shfl_xor(v, o, 64);
    return v;
}
__device__ __forceinline__ float qsum8(float v) {
    v += __shfl_xor(v, 1, 64);
    v += __shfl_xor(v, 2, 64);
    v += __shfl_xor(v, 4, 64);
    return v;
}
__device__ __forceinline__ float gsum8f(float v) {
    v += __shfl_xor(v, 8, 64);
    v += __shfl_xor(v, 16, 64);
    v += __shfl_xor(v, 32, 64);
    return v;
}

// item-first node order
__device__ __forceinline__ int orderIF(int i) {
    return (i < NITEM) ? (NUSER + i) : (i - NITEM);
}

// ---------------- CSR build ----------------
__global__ void k_hist(const int* ei, int E2, int E, int* cnt, int* posw) {
    int i = blockIdx.x * blockDim.x + threadIdx.x;
    if (i >= E2) return;
    int d = (i < E) ? ei[E + i] : ei[i - E];
    posw[i] = atomicAdd(&cnt[d], 1);
}

__global__ void k_bsum(const int* __restrict__ cnt, int* __restrict__ bsum, int n, int chunk) {
    __shared__ int wsh[4];
    int b = blockIdx.x, tid = threadIdx.x;
    int base = b * chunk, end = min(n, base + chunk);
    int s = 0;
    for (int i = base + tid; i < end; i += 256) s += cnt[i];
#pragma unroll
    for (int o = 32; o > 0; o >>= 1) s += __shfl_xor(s, o, 64);
    if ((tid & 63) == 0) wsh[tid >> 6] = s;
    __syncthreads();
    if (tid == 0) bsum[b] = wsh[0] + wsh[1] + wsh[2] + wsh[3];
}

__global__ void k_bscan(int* bsum, int nb, int* rp_end) {
    int lane = threadIdx.x;
    int v = (lane < nb) ? bsum[lane] : 0;
    int orig = v;
#pragma unroll
    for (int o = 1; o < 64; o <<= 1) {
        int y = __shfl_up(v, o, 64);
        if (lane >= o) v += y;
    }
    if (lane < nb) bsum[lane] = v - orig;
    if (lane == 63) *rp_end = v;
}

__global__ void k_apply(const int* __restrict__ cnt, const int* __restrict__ boff,
                        int* __restrict__ rp, int n, int chunk) {
    __shared__ int buf[256];
    __shared__ int csh;
    int b = blockIdx.x, tid = threadIdx.x;
    int base = b * chunk, end = min(n, base + chunk);
    int carry = boff[b];
    for (int t0 = base; t0 < end; t0 += 256) {
        int i = t0 + tid;
        int v = (i < end) ? cnt[i] : 0;
        int x = v;
        buf[tid] = x;
        __syncthreads();
        for (int o = 1; o < 256; o <<= 1) {
            int y = (tid >= o) ? buf[tid - o] : 0;
            __syncthreads();
            x += y;
            buf[tid] = x;
            __syncthreads();
        }
        if (i < end) rp[i] = carry + x - v;
        __syncthreads();
        if (tid == 255) csh = carry + x;
        __syncthreads();
        carry = csh;
    }
}

__global__ void k_scatter(const int* ei, int E2, int E, const int* rp,
                          const int* __restrict__ posw, int* col) {
    int i = blockIdx.x * blockDim.x + threadIdx.x;
    if (i >= E2) return;
    int j = (i < E) ? i : i - E;
    int s = (i < E) ? ei[j] : ei[E + j];
    int d = (i < E) ? ei[E + j] : ei[j];
    col[rp[d] + posw[i]] = s;
}

// ---------------- node prep ----------------
__global__ void k_prep_pref(const float* __restrict__ pv, const float* __restrict__ pa,
                            const float* __restrict__ pt, __half* __restrict__ M) {
    int t = blockIdx.x * blockDim.x + threadIdx.x;
    int w = t >> 6, lane = t & 63, nw = (gridDim.x * blockDim.x) >> 6;
    for (int r = w; r < NUSER; r += nw) {
        float a = pv[(size_t)r * DD + lane];
        float b = pa[(size_t)r * DD + lane];
        float c = pt[(size_t)r * DD + lane];
        float sa = a * a, sb = b * b, sc = c * c;
#pragma unroll
        for (int o = 32; o > 0; o >>= 1) {
            sa += __shfl_xor(sa, o, 64);
            sb += __shfl_xor(sb, o, 64);
            sc += __shfl_xor(sc, o, 64);
        }
        size_t base = (size_t)r * 3 * DD + lane;
        M[base] = __float2half(a / fmaxf(sqrtf(sa), 1e-12f));
        M[base + DD] = __float2half(b / fmaxf(sqrtf(sb), 1e-12f));
        M[base + 2 * DD] = __float2half(c / fmaxf(sqrtf(sc), 1e-12f));
    }
}

template <int K>
__global__ void k_mlp(const float* __restrict__ feat, const float* __restrict__ W,
                      const float* __restrict__ bias, __half* __restrict__ M, int mo) {
    constexpr int K4 = K / 4;
    __shared__ float4 Wl[K4][DD];
    __shared__ float4 rbuf[4][2][K4];
    int t = threadIdx.x, wib = t >> 6, lane = t & 63;
    for (int i = t; i < DD * K4; i += 256) {
        int c = i / K4, k4 = i - c * K4;
        Wl[k4][c] = *(const float4*)(W + (size_t)c * K + k4 * 4);
    }
    __syncthreads();
    float b = bias[lane];
    const int stride = gridDim.x * 4;
    int r = blockIdx.x * 4 + wib;
    float4 v = {0.f, 0.f, 0.f, 0.f};
    if (r < NITEM && lane < K4) v = *(const float4*)(feat + (size_t)r * K + lane * 4);
    int cur = 0;
    for (; r < NITEM; r += stride) {
        if (lane < K4) rbuf[wib][cur][lane] = v;
        int rn = r + stride;
        if (rn < NITEM && lane < K4) v = *(const float4*)(feat + (size_t)rn * K + lane * 4);
        asm volatile("s_waitcnt lgkmcnt(0)" ::: "memory");
        float acc = b;
#pragma unroll
        for (int k4 = 0; k4 < K4; k4++) {
            float4 x4 = rbuf[wib][cur][k4];
            float4 w4 = Wl[k4][lane];
            acc += x4.x * w4.x + x4.y * w4.y + x4.z * w4.z + x4.w * w4.w;
        }
        float h = acc > 0.f ? acc : 0.01f * acc;
        float n = sqrtf(wsum(h * h));
        M[((size_t)(NUSER + r) * 3 + mo) * DD + lane] = __float2half(h / fmaxf(n, 1e-12f));
        cur ^= 1;
    }
}

// ---------------- MFMA GEMM: fp16 interleaved-3 in/out ----------------
__global__ void k_gemm_mfma(const __half* __restrict__ x3, const float* __restrict__ W3,
                            __half* __restrict__ o3) {
    int mo = blockIdx.y;
    const float* W = W3 + (size_t)mo * 4096;
    int t = threadIdx.x, wv = t >> 6, lane = t & 63;
    int lr = lane & 15, lg = lane >> 4;
    half8v b[4][2];
#pragma unroll
    for (int ct = 0; ct < 4; ct++)
#pragma unroll
        for (int kh = 0; kh < 2; kh++)
#pragma unroll
            for (int i = 0; i < 8; i++)
                b[ct][kh][i] = (_Float16)W[(kh * 32 + lg * 8 + i) * 64 + ct * 16 + lr];
    const int NT = NN / 16;
    for (int rt = blockIdx.x * 4 + wv; rt < NT; rt += gridDim.x * 4) {
        const __half* xr = x3 + ((size_t)(rt * 16 + lr) * 3 + mo) * DD + lg * 8;
        half8v a0 = *(const half8v*)xr;
        half8v a1 = *(const half8v*)(xr + 32);
        float4v acc0 = {0.f, 0.f, 0.f, 0.f}, acc1 = acc0, acc2 = acc0, acc3 = acc0;
        acc0 = __builtin_amdgcn_mfma_f32_16x16x32_f16(a0, b[0][0], acc0, 0, 0, 0);
        acc1 = __builtin_amdgcn_mfma_f32_16x16x32_f16(a0, b[1][0], acc1, 0, 0, 0);
        acc2 = __builtin_amdgcn_mfma_f32_16x16x32_f16(a0, b[2][0], acc2, 0, 0, 0);
        acc3 = __builtin_amdgcn_mfma_f32_16x16x32_f16(a0, b[3][0], acc3, 0, 0, 0);
        acc0 = __builtin_amdgcn_mfma_f32_16x16x32_f16(a1, b[0][1], acc0, 0, 0, 0);
        acc1 = __builtin_amdgcn_mfma_f32_16x16x32_f16(a1, b[1][1], acc1, 0, 0, 0);
        acc2 = __builtin_amdgcn_mfma_f32_16x16x32_f16(a1, b[2][1], acc2, 0, 0, 0);
        acc3 = __builtin_amdgcn_mfma_f32_16x16x32_f16(a1, b[3][1], acc3, 0, 0, 0);
#pragma unroll
        for (int i = 0; i < 4; i++) {
            size_t rbase = ((size_t)(rt * 16 + lg * 4 + i) * 3 + mo) * DD + lr;
            o3[rbase] = __float2half(acc0[i]);
            o3[rbase + 16] = __float2half(acc1[i]);
            o3[rbase + 32] = __float2half(acc2[i]);
            o3[rbase + 48] = __float2half(acc3[i]);
        }
    }
}

__global__ void k_gemm_f2(const float* __restrict__ x, const float* __restrict__ W2,
                          __half* __restrict__ o2) {
    __shared__ float rowbuf[4][DD];
    int mo = blockIdx.y;
    const float* W = W2 + (size_t)mo * 4096;
    int t = threadIdx.x, wib = t >> 6, lane = t & 63;
    float Wc[DD];
#pragma unroll
    for (int k = 0; k < DD; k++) Wc[k] = W[k * DD + lane];
    for (int r = blockIdx.x * 4 + wib; r < NN; r += gridDim.x * 4) {
        rowbuf[wib][lane] = x[(size_t)r * DD + lane];
        asm volatile("s_waitcnt lgkmcnt(0)" ::: "memory");
        float acc = 0.f;
#pragma unroll
        for (int k4 = 0; k4 < DD / 4; k4++) {
            float4 xq = *(const float4*)&rowbuf[wib][k4 * 4];
            acc += xq.x * Wc[k4 * 4] + xq.y * Wc[k4 * 4 + 1] + xq.z * Wc[k4 * 4 + 2] +
                   xq.w * Wc[k4 * 4 + 3];
        }
        o2[((size_t)r * 2 + mo) * DD + lane] = __float2half(acc);
    }
}

__global__ void k_gemm_id(const float* __restrict__ x, const float* __restrict__ W,
                          __half* __restrict__ hout, float* __restrict__ xnorm) {
    __shared__ float rowbuf[4][DD];
    int t = threadIdx.x, wib = t >> 6, lane = t & 63;
    float Wc[DD];
#pragma unroll
    for (int k = 0; k < DD; k++) Wc[k] = W[k * DD + lane];
    for (int r = blockIdx.x * 4 + wib; r < NN; r += gridDim.x * 4) {
        float xv = x[(size_t)r * DD + lane];
        float n = sqrtf(wsum(xv * xv));
        xv /= fmaxf(n, 1e-12f);
        xnorm[(size_t)r * DD + lane] = xv;
        rowbuf[wib][lane] = xv;
        asm volatile("s_waitcnt lgkmcnt(0)" ::: "memory");
        float acc = 0.f;
#pragma unroll
        for (int k4 = 0; k4 < DD / 4; k4++) {
            float4 xq = *(const float4*)&rowbuf[wib][k4 * 4];
            acc += xq.x * Wc[k4 * 4] + xq.y * Wc[k4 * 4 + 1] + xq.z * Wc[k4 * 4 + 2] +
                   xq.w * Wc[k4 * 4 + 3];
        }
        hout[(size_t)r * DD + lane] = __float2half(acc);
    }
}

// ---------------- fused GAT pre + inline gates + gcn layer1 ----------------
__device__ __forceinline__ float gatef(float ssum) {
    float gate = 1.f / (1.f + __expf(-0.5f * ssum));
    return gate > 0.5f ? gate : 1.f;
}

__global__ void k_gat_pre3(const __half* __restrict__ M, const __half* __restrict__ h3,
                           const __half* __restrict__ g1, const int* __restrict__ rp,
                           const int* __restrict__ col, __half* __restrict__ x3h,
                           float* __restrict__ h1f) {
    int t = blockIdx.x * blockDim.x + threadIdx.x;
    int wv = t >> 6, lane = t & 63, nw = (gridDim.x * blockDim.x) >> 6;
    int g = lane >> 3, q = lane & 7;
    const __half2 z = __floats2half2_rn(0.f, 0.f);
    for (int w0 = wv; w0 < NN; w0 += nw) {
        int n = orderIF(w0);
        int e0 = rp[n], e1 = rp[n + 1];
        const uint4* mrow = (const uint4*)(M + (size_t)n * 192);
        uint4 tv = mrow[q], ta = mrow[q + 8], tt = mrow[q + 16];
        const uint4* hrow = (const uint4*)(h3 + (size_t)n * 192);
        uint4 hd0 = hrow[q], hd1 = hrow[q + 8], hd2 = hrow[q + 16];
        float s0 = 0.f, s1 = 0.f, s2 = 0.f;
        __half2 a0[4] = {z, z, z, z}, a1[4] = {z, z, z, z}, a2[4] = {z, z, z, z};
        __half2 ag[4] = {z, z, z, z};
        for (int eb = e0 + g; eb < e1; eb += 8) {
            int sn = col[eb];
            const uint4* srow = (const uint4*)(M + (size_t)sn * 192);
            uint4 sv = srow[q], sa = srow[q + 8], st = srow[q + 16];
            float dv = qsum8(dot8(tv, sv));
            float da = qsum8(dot8(ta, sa));
            float dt = qsum8(dot8(tt, st));
            float ga = gatef(da + dt), gb_ = gatef(dv + dt), gc = gatef(da + dv);
            const uint4* hsrow = (const uint4*)(h3 + (size_t)sn * 192);
            uint4 v0 = hsrow[q], v1 = hsrow[q + 8], v2 = hsrow[q + 16];
            uint4 vg = ((const uint4*)(g1 + (size_t)sn * DD))[q];
            float d0 = qsum8(dot8(hd0, v0));
            float d1 = qsum8(dot8(hd1, v1));
            float d2 = qsum8(dot8(hd2, v2));
            float sc0 = d0 > 0.f ? d0 : 0.2f * d0;
            float sc1 = d1 > 0.f ? d1 : 0.2f * d1;
            float sc2 = d2 > 0.f ? d2 : 0.2f * d2;
            float p0 = __expf(sc0), p1 = __expf(sc1), p2 = __expf(sc2);
            s0 += p0;
            s1 += p1;
            s2 += p2;
            __half2 ph0 = __float2half2_rn(p0 * ga);
            __half2 ph1 = __float2half2_rn(p1 * gb_);
            __half2 ph2 = __float2half2_rn(p2 * gc);
            a0[0] = __hfma2(ph0, uh(v0.x), a0[0]);
            a0[1] = __hfma2(ph0, uh(v0.y), a0[1]);
            a0[2] = __hfma2(ph0, uh(v0.z), a0[2]);
            a0[3] = __hfma2(ph0, uh(v0.w), a0[3]);
            a1[0] = __hfma2(ph1, uh(v1.x), a1[0]);
            a1[1] = __hfma2(ph1, uh(v1.y), a1[1]);
            a1[2] = __hfma2(ph1, uh(v1.z), a1[2]);
            a1[3] = __hfma2(ph1, uh(v1.w), a1[3]);
            a2[0] = __hfma2(ph2, uh(v2.x), a2[0]);
            a2[1] = __hfma2(ph2, uh(v2.y), a2[1]);
            a2[2] = __hfma2(ph2, uh(v2.z), a2[2]);
            a2[3] = __hfma2(ph2, uh(v2.w), a2[3]);
            ag[0] = __hadd2(ag[0], uh(vg.x));
            ag[1] = __hadd2(ag[1], uh(vg.y));
            ag[2] = __hadd2(ag[2], uh(vg.z));
            ag[3] = __hadd2(ag[3], uh(vg.w));
        }
        s0 = gsum8f(s0);
        s1 = gsum8f(s1);
        s2 = gsum8f(s2);
#pragma unroll
        for (int j = 0; j < 4; j++) {
            a0[j] = h2rx(h2rx(h2rx(a0[j], 8), 16), 32);
            a1[j] = h2rx(h2rx(h2rx(a1[j], 8), 16), 32);
            a2[j] = h2rx(h2rx(h2rx(a2[j], 8), 16), 32);
            ag[j] = h2rx(h2rx(h2rx(ag[j], 8), 16), 32);
        }
        float i0 = 1.f / (s0 + 1e-16f), i1 = 1.f / (s1 + 1e-16f), i2 = 1.f / (s2 + 1e-16f);
        float o0[8], o1[8], o2[8];
#pragma unroll
        for (int j = 0; j < 4; j++) {
            float2 f0 = __half22float2(a0[j]);
            float2 f1 = __half22float2(a1[j]);
            float2 f2 = __half22float2(a2[j]);
            o0[2 * j] = f0.x * i0;
            o0[2 * j + 1] = f0.y * i0;
            o1[2 * j] = f1.x * i1;
            o1[2 * j + 1] = f1.y * i1;
            o2[2 * j] = f2.x * i2;
            o2[2 * j + 1] = f2.y * i2;
        }
        float n0 = 0.f, n1 = 0.f, n2 = 0.f;
#pragma unroll
        for (int k = 0; k < 8; k++) {
            n0 += o0[k] * o0[k];
            n1 += o1[k] * o1[k];
            n2 += o2[k] * o2[k];
        }
        n0 = qsum8(n0);
        n1 = qsum8(n1);
        n2 = qsum8(n2);
        float r0 = 1.f / fmaxf(sqrtf(n0), 1e-12f);
        float r1 = 1.f / fmaxf(sqrtf(n1), 1e-12f);
        float r2 = 1.f / fmaxf(sqrtf(n2), 1e-12f);
        if (g == 0) {
            uint4* orow = (uint4*)(x3h + (size_t)n * 192);
            uint4 w0_, w1_, w2_;
            w0_.x = hu(__floats2half2_rn(o0[0] * r0, o0[1] * r0));
            w0_.y = hu(__floats2half2_rn(o0[2] * r0, o0[3] * r0));
            w0_.z = hu(__floats2half2_rn(o0[4] * r0, o0[5] * r0));
            w0_.w = hu(__floats2half2_rn(o0[6] * r0, o0[7] * r0));
            w1_.x = hu(__floats2half2_rn(o1[0] * r1, o1[1] * r1));
            w1_.y = hu(__floats2half2_rn(o1[2] * r1, o1[3] * r1));
            w1_.z = hu(__floats2half2_rn(o1[4] * r1, o1[5] * r1));
            w1_.w = hu(__floats2half2_rn(o1[6] * r1, o1[7] * r1));
            w2_.x = hu(__floats2half2_rn(o2[0] * r2, o2[1] * r2));
            w2_.y = hu(__floats2half2_rn(o2[2] * r2, o2[3] * r2));
            w2_.z = hu(__floats2half2_rn(o2[4] * r2, o2[5] * r2));
            w2_.w = hu(__floats2half2_rn(o2[6] * r2, o2[7] * r2));
            orow[q] = w0_;
            orow[q + 8] = w1_;
            orow[q + 16] = w2_;
            float og[8];
#pragma unroll
            for (int j = 0; j < 4; j++) {
                float2 f = __half22float2(ag[j]);
                og[2 * j] = f.x > 0.f ? f.x : 0.01f * f.x;
                og[2 * j + 1] = f.y > 0.f ? f.y : 0.01f * f.y;
            }
            float* ob = h1f + (size_t)n * DD + q * 8;
            *(float4*)(ob) = make_float4(og[0], og[1], og[2], og[3]);
            *(float4*)(ob + 4) = make_float4(og[4], og[5], og[6], og[7]);
        }
    }
}

// ---------------- fused 3-modality GAT ori (intermediate iterations) ----------------
__global__ void k_gat_ori3(const __half* __restrict__ h3, const __half* __restrict__ x3h,
                           const int* __restrict__ rp, const int* __restrict__ col,
                           __half* __restrict__ xout) {
    int t = blockIdx.x * blockDim.x + threadIdx.x;
    int wv = t >> 6, lane = t & 63, nw = (gridDim.x * blockDim.x) >> 6;
    int g = lane >> 3, q = lane & 7;
    const __half2 z = __floats2half2_rn(0.f, 0.f);
    for (int w0 = wv; w0 < NN; w0 += nw) {
        int n = orderIF(w0);
        int e0 = rp[n], e1 = rp[n + 1];
        const uint4* hrow = (const uint4*)(h3 + (size_t)n * 192);
        uint4 hd0 = hrow[q], hd1 = hrow[q + 8], hd2 = hrow[q + 16];
        float s0 = 0.f, s1 = 0.f, s2 = 0.f;
        __half2 a0[4] = {z, z, z, z}, a1[4] = {z, z, z, z}, a2[4] = {z, z, z, z};
        for (int eb = e0 + g; eb < e1; eb += 8) {
            int sn = col[eb];
            const uint4* srow = (const uint4*)(h3 + (size_t)sn * 192);
            uint4 v0 = srow[q], v1 = srow[q + 8], v2 = srow[q + 16];
            float d0 = qsum8(dot8(hd0, v0));
            float d1 = qsum8(dot8(hd1, v1));
            float d2 = qsum8(dot8(hd2, v2));
            float sc0 = d0 > 0.f ? d0 : 0.2f * d0;
            float sc1 = d1 > 0.f ? d1 : 0.2f * d1;
            float sc2 = d2 > 0.f ? d2 : 0.2f * d2;
            float p0 = __expf(sc0), p1 = __expf(sc1), p2 = __expf(sc2);
            s0 += p0;
            s1 += p1;
            s2 += p2;
            __half2 ph0 = __float2half2_rn(p0);
            __half2 ph1 = __float2half2_rn(p1);
            __half2 ph2 = __float2half2_rn(p2);
            a0[0] = __hfma2(ph0, uh(v0.x), a0[0]);
            a0[1] = __hfma2(ph0, uh(v0.y), a0[1]);
            a0[2] = __hfma2(ph0, uh(v0.z), a0[2]);
            a0[3] = __hfma2(ph0, uh(v0.w), a0[3]);
            a1[0] = __hfma2(ph1, uh(v1.x), a1[0]);
            a1[1] = __hfma2(ph1, uh(v1.y), a1[1]);
            a1[2] = __hfma2(ph1, uh(v1.z), a1[2]);
            a1[3] = __hfma2(ph1, uh(v1.w), a1[3]);
            a2[0] = __hfma2(ph2, uh(v2.x), a2[0]);
            a2[1] = __hfma2(ph2, uh(v2.y), a2[1]);
            a2[2] = __hfma2(ph2, uh(v2.z), a2[2]);
            a2[3] = __hfma2(ph2, uh(v2.w), a2[3]);
        }
        s0 = gsum8f(s0);
        s1 = gsum8f(s1);
        s2 = gsum8f(s2);
#pragma unroll
        for (int j = 0; j < 4; j++) {
            a0[j] = h2rx(h2rx(h2rx(a0[j], 8), 16), 32);
            a1[j] = h2rx(h2rx(h2rx(a1[j], 8), 16), 32);
            a2[j] = h2rx(h2rx(h2rx(a2[j], 8), 16), 32);
        }
        float i0 = 1.f / (s0 + 1e-16f), i1 = 1.f / (s1 + 1e-16f), i2 = 1.f / (s2 + 1e-16f);
        const uint4* xrow = (const uint4*)(x3h + (size_t)n * 192);
        uint4 xr0 = xrow[q], xr1 = xrow[q + 8], xr2 = xrow[q + 16];
        float o0[8], o1[8], o2[8];
#pragma unroll
        for (int j = 0; j < 4; j++) {
            float2 f0 = __half22float2(a0[j]);
            float2 f1 = __half22float2(a1[j]);
            float2 f2 = __half22float2(a2[j]);
            float2 xf0 = __half22float2(uh(j == 0 ? xr0.x : j == 1 ? xr0.y : j == 2 ? xr0.z : xr0.w));
            float2 xf1 = __half22float2(uh(j == 0 ? xr1.x : j == 1 ? xr1.y : j == 2 ? xr1.z : xr1.w));
            float2 xf2 = __half22float2(uh(j == 0 ? xr2.x : j == 1 ? xr2.y : j == 2 ? xr2.z : xr2.w));
            o0[2 * j] = xf0.x + f0.x * i0;
            o0[2 * j + 1] = xf0.y + f0.y * i0;
            o1[2 * j] = xf1.x + f1.x * i1;
            o1[2 * j + 1] = xf1.y + f1.y * i1;
            o2[2 * j] = xf2.x + f2.x * i2;
            o2[2 * j + 1] = xf2.y + f2.y * i2;
        }
        float n0 = 0.f, n1 = 0.f, n2 = 0.f;
#pragma unroll
        for (int k = 0; k < 8; k++) {
            n0 += o0[k] * o0[k];
            n1 += o1[k] * o1[k];
            n2 += o2[k] * o2[k];
        }
        n0 = qsum8(n0);
        n1 = qsum8(n1);
        n2 = qsum8(n2);
        float r0 = 1.f / fmaxf(sqrtf(n0), 1e-12f);
        float r1 = 1.f / fmaxf(sqrtf(n1), 1e-12f);
        float r2 = 1.f / fmaxf(sqrtf(n2), 1e-12f);
        if (g == 0) {
            uint4* orow = (uint4*)(xout + (size_t)n * 192);
            uint4 w0_, w1_, w2_;
            w0_.x = hu(__floats2half2_rn(o0[0] * r0, o0[1] * r0));
            w0_.y = hu(__floats2half2_rn(o0[2] * r0, o0[3] * r0));
            w0_.z = hu(__floats2half2_rn(o0[4] * r0, o0[5] * r0));
            w0_.w = hu(__floats2half2_rn(o0[6] * r0, o0[7] * r0));
            w1_.x = hu(__floats2half2_rn(o1[0] * r1, o1[1] * r1));
            w1_.y = hu(__floats2half2_rn(o1[2] * r1, o1[3] * r1));
            w1_.z = hu(__floats2half2_rn(o1[4] * r1, o1[5] * r1));
            w1_.w = hu(__floats2half2_rn(o1[6] * r1, o1[7] * r1));
            w2_.x = hu(__floats2half2_rn(o2[0] * r2, o2[1] * r2));
            w2_.y = hu(__floats2half2_rn(o2[2] * r2, o2[3] * r2));
            w2_.z = hu(__floats2half2_rn(o2[4] * r2, o2[5] * r2));
            w2_.w = hu(__floats2half2_rn(o2[6] * r2, o2[7] * r2));
            orow[q] = w0_;
            orow[q + 8] = w1_;
            orow[q + 16] = w2_;
        }
    }
}

// ---------------- final GAT ori fused with gcn layers 2+3 + 4-way sum ----------------
__global__ void k_gat_ori3f(const __half* __restrict__ h3, const __half* __restrict__ x3h,
                            const __half* __restrict__ gp, const float* __restrict__ x0,
                            const float* __restrict__ h1, const int* __restrict__ rp,
                            const int* __restrict__ col, float* __restrict__ out) {
    int t = blockIdx.x * blockDim.x + threadIdx.x;
    int wv = t >> 6, lane = t & 63, nw = (gridDim.x * blockDim.x) >> 6;
    int g = lane >> 3, q = lane & 7;
    const __half2 z = __floats2half2_rn(0.f, 0.f);
    for (int w0 = wv; w0 < NN; w0 += nw) {
        int n = orderIF(w0);
        int e0 = rp[n], e1 = rp[n + 1];
        const uint4* hrow = (const uint4*)(h3 + (size_t)n * 192);
        uint4 hd0 = hrow[q], hd1 = hrow[q + 8], hd2 = hrow[q + 16];
        float s0 = 0.f, s1 = 0.f, s2 = 0.f;
        __half2 a0[4] = {z, z, z, z}, a1[4] = {z, z, z, z}, a2[4] = {z, z, z, z};
        __half2 aA[4] = {z, z, z, z}, aB[4] = {z, z, z, z};
        for (int eb = e0 + g; eb < e1; eb += 8) {
            int sn = col[eb];
            const uint4* srow = (const uint4*)(h3 + (size_t)sn * 192);
            uint4 v0 = srow[q], v1 = srow[q + 8], v2 = srow[q + 16];
            const uint4* gbase = (const uint4*)(gp + (size_t)sn * 128);
            uint4 vA = gbase[q], vB = gbase[q + 8];
            float d0 = qsum8(dot8(hd0, v0));
            float d1 = qsum8(dot8(hd1, v1));
            float d2 = qsum8(dot8(hd2, v2));
            float sc0 = d0 > 0.f ? d0 : 0.2f * d0;
            float sc1 = d1 > 0.f ? d1 : 0.2f * d1;
            float sc2 = d2 > 0.f ? d2 : 0.2f * d2;
            float p0 = __expf(sc0), p1 = __expf(sc1), p2 = __expf(sc2);
            s0 += p0;
            s1 += p1;
            s2 += p2;
            __half2 ph0 = __float2half2_rn(p0);
            __half2 ph1 = __float2half2_rn(p1);
            __half2 ph2 = __float2half2_rn(p2);
            a0[0] = __hfma2(ph0, uh(v0.x), a0[0]);
            a0[1] = __hfma2(ph0, uh(v0.y), a0[1]);
            a0[2] = __hfma2(ph0, uh(v0.z), a0[2]);
            a0[3] = __hfma2(ph0, uh(v0.w), a0[3]);
            a1[0] = __hfma2(ph1, uh(v1.x), a1[0]);
            a1[1] = __hfma2(ph1, uh(v1.y), a1[1]);
            a1[2] = __hfma2(ph1, uh(v1.z), a1[2]);
            a1[3] = __hfma2(ph1, uh(v1.w), a1[3]);
            a2[0] = __hfma2(ph2, uh(v2.x), a2[0]);
            a2[1] = __hfma2(ph2, uh(v2.y), a2[1]);
            a2[2] = __hfma2(ph2, uh(v2.z), a2[2]);
            a2[3] = __hfma2(ph2, uh(v2.w), a2[3]);
            aA[0] = __hadd2(aA[0], uh(vA.x));
            aA[1] = __hadd2(aA[1], uh(vA.y));
            aA[2] = __hadd2(aA[2], uh(vA.z));
            aA[3] = __hadd2(aA[3], uh(vA.w));
            aB[0] = __hadd2(aB[0], uh(vB.x));
            aB[1] = __hadd2(aB[1], uh(vB.y));
            aB[2] = __hadd2(aB[2], uh(vB.z));
            aB[3] = __hadd2(aB[3], uh(vB.w));
        }
        s0 = gsum8f(s0);
        s1 = gsum8f(s1);
        s2 = gsum8f(s2);
#pragma unroll
        for (int j = 0; j < 4; j++) {
            a0[j] = h2rx(h2rx(h2rx(a0[j], 8), 16), 32);
            a1[j] = h2rx(h2rx(h2rx(a1[j], 8), 16), 32);
            a2[j] = h2rx(h2rx(h2rx(a2[j], 8), 16), 32);
            aA[j] = h2rx(h2rx(h2rx(aA[j], 8), 16), 32);
            aB[j] = h2rx(h2rx(h2rx(aB[j], 8), 16), 32);
        }
        float i0 = 1.f / (s0 + 1e-16f), i1 = 1.f / (s1 + 1e-16f), i2 = 1.f / (s2 + 1e-16f);
        const uint4* xrow = (const uint4*)(x3h + (size_t)n * 192);
        uint4 xr0 = xrow[q], xr1 = xrow[q + 8], xr2 = xrow[q + 16];
        float o0[8], o1[8], o2[8];
#pragma unroll
        for (int j = 0; j < 4; j++) {
            float2 f0 = __half22float2(a0[j]);
            float2 f1 = __half22float2(a1[j]);
            float2 f2 = __half22float2(a2[j]);
            float2 xf0 = __half22float2(uh(j == 0 ? xr0.x : j == 1 ? xr0.y : j == 2 ? xr0.z : xr0.w));
            float2 xf1 = __half22float2(uh(j == 0 ? xr1.x : j == 1 ? xr1.y : j == 2 ? xr1.z : xr1.w));
            float2 xf2 = __half22float2(uh(j == 0 ? xr2.x : j == 1 ? xr2.y : j == 2 ? xr2.z : xr2.w));
            o0[2 * j] = xf0.x + f0.x * i0;
            o0[2 * j + 1] = xf0.y + f0.y * i0;
            o1[2 * j] = xf1.x + f1.x * i1;
            o1[2 * j + 1] = xf1.y + f1.y * i1;
            o2[2 * j] = xf2.x + f2.x * i2;
            o2[2 * j + 1] = xf2.y + f2.y * i2;
        }
        float n0 = 0.f, n1 = 0.f, n2 = 0.f;
#pragma unroll
        for (int k = 0; k < 8; k++) {
            n0 += o0[k] * o0[k];
            n1 += o1[k] * o1[k];
            n2 += o2[k] * o2[k];
        }
        n0 = qsum8(n0);
        n1 = qsum8(n1);
        n2 = qsum8(n2);
        float r0 = 1.f / fmaxf(sqrtf(n0), 1e-12f);
        float r1 = 1.f / fmaxf(sqrtf(n1), 1e-12f);
        float r2 = 1.f / fmaxf(sqrtf(n2), 1e-12f);
        if (g == 0) {
            float* ob = out + (size_t)n * 256 + q * 8;
            // gcn: out[:, :64] = x0 + h1 + leaky(convA) + convB
            const float* p0 = x0 + (size_t)n * DD + q * 8;
            const float* p1 = h1 + (size_t)n * DD + q * 8;
            float4 v0a = *(const float4*)(p0), v0b = *(const float4*)(p0 + 4);
            float4 v1a = *(const float4*)(p1), v1b = *(const float4*)(p1 + 4);
            float og[8];
#pragma unroll
            for (int j = 0; j < 4; j++) {
                float2 fA = __half22float2(aA[j]);
                float2 fB = __half22float2(aB[j]);
                float hx = fA.x > 0.f ? fA.x : 0.01f * fA.x;
                float hy = fA.y > 0.f ? fA.y : 0.01f * fA.y;
                og[2 * j] = hx + fB.x;
                og[2 * j + 1] = hy + fB.y;
            }
            *(float4*)(ob) = make_float4(og[0] + v0a.x + v1a.x, og[1] + v0a.y + v1a.y,
                                         og[2] + v0a.z + v1a.z, og[3] + v0a.w + v1a.w);
            *(float4*)(ob + 4) = make_float4(og[4] + v0b.x + v1b.x, og[5] + v0b.y + v1b.y,
                                             og[6] + v0b.z + v1b.z, og[7] + v0b.w + v1b.w);
            // gat modalities: cols 64..255
            *(float4*)(ob + 64) = make_float4(o0[0] * r0, o0[1] * r0, o0[2] * r0, o0[3] * r0);
            *(float4*)(ob + 68) = make_float4(o0[4] * r0, o0[5] * r0, o0[6] * r0, o0[7] * r0);
            *(float4*)(ob + 128) = make_float4(o1[0] * r1, o1[1] * r1, o1[2] * r1, o1[3] * r1);
            *(float4*)(ob + 132) = make_float4(o1[4] * r1, o1[5] * r1, o1[6] * r1, o1[7] * r1);
            *(float4*)(ob + 192) = make_float4(o2[0] * r2, o2[1] * r2, o2[2] * r2, o2[3] * r2);
            *(float4*)(ob + 196) = make_float4(o2[4] * r2, o2[5] * r2, o2[6] * r2, o2[7] * r2);
        }
    }
}

extern "C" void kernel_launch(void* const* d_in, const int* in_sizes, int n_in,
                              void* d_out, int out_size, void* d_ws, size_t ws_size,
                              hipStream_t stream) {
    const int* ei       = (const int*)d_in[0];
    const float* v_feat = (const float*)d_in[1];
    const float* a_feat = (const float*)d_in[2];
    const float* t_feat = (const float*)d_in[3];
    const float* pref_v = (const float*)d_in[4];
    const float* pref_a = (const float*)d_in[5];
    const float* pref_t = (const float*)d_in[6];
    const float* mlp_v_w = (const float*)d_in[7];
    const float* mlp_v_b = (const float*)d_in[8];
    const float* mlp_a_w = (const float*)d_in[9];
    const float* mlp_a_b = (const float*)d_in[10];
    const float* mlp_t_w = (const float*)d_in[11];
    const float* mlp_t_b = (const float*)d_in[12];
    const float* pre_w  = (const float*)d_in[13];
    const float* ori_w  = (const float*)d_in[14];
    const float* gcn_w  = (const float*)d_in[15];
    const float* id_emb = (const float*)d_in[16];
    float* out = (float*)d_out;

    const int E2 = in_sizes[0];
    const int E  = E2 / 2;

    char* w = (char*)d_ws;
    auto alloc = [&](size_t bytes) -> void* {
        void* p = (void*)w;
        w += (bytes + 255) & ~(size_t)255;
        return p;
    };
    int* cnt  = (int*)alloc((size_t)NN * 4);
    int* rp   = (int*)alloc((size_t)(NN + 1) * 4);
    int* bsum = (int*)alloc(256);
    int* col  = (int*)alloc((size_t)E2 * 4);
    int* posw = (int*)alloc((size_t)E2 * 4);
    __half* Mh3  = (__half*)alloc(3 * PLANE * 2);
    __half* hb3h = (__half*)alloc(3 * PLANE * 2);
    __half* x3h  = (__half*)alloc(3 * PLANE * 2);
    __half* g1   = (__half*)alloc(PLANE * 2);
    __half* gpair = (__half*)alloc(2 * PLANE * 2);
    float* x0f = (float*)alloc(PLANE * 4);
    float* h1f = (float*)alloc(PLANE * 4);

    // ---- CSR by destination ----
    const int NBLK = 64, CHUNK = (NN + NBLK - 1) / NBLK;
    hipMemsetAsync(cnt, 0, (size_t)NN * 4, stream);
    k_hist<<<(E2 + 255) / 256, 256, 0, stream>>>(ei, E2, E, cnt, posw);
    k_bsum<<<NBLK, 256, 0, stream>>>(cnt, bsum, NN, CHUNK);
    k_bscan<<<1, 64, 0, stream>>>(bsum, NBLK, rp + NN);
    k_apply<<<NBLK, 256, 0, stream>>>(cnt, bsum, rp, NN, CHUNK);
    k_scatter<<<(E2 + 255) / 256, 256, 0, stream>>>(ei, E2, E, rp, posw, col);

    // ---- node tables (interleaved fp16) ----
    k_prep_pref<<<640, 256, 0, stream>>>(pref_v, pref_a, pref_t, Mh3);
    k_mlp<128><<<1024, 256, 0, stream>>>(v_feat, mlp_v_w, mlp_v_b, Mh3, 0);
    k_mlp<128><<<1024, 256, 0, stream>>>(a_feat, mlp_a_w, mlp_a_b, Mh3, 1);
    k_mlp<100><<<1024, 256, 0, stream>>>(t_feat, mlp_t_w, mlp_t_b, Mh3, 2);

    const int GB = (NN + 3) / 4;  // one wave per node

    // ---- gcn layer 0 (id l2norm + gemm) before the fused pre pass ----
    k_gemm_id<<<1280, 256, 0, stream>>>(id_emb, gcn_w, g1, x0f);

    // ---- gat_pre fused with gates + gcn conv1 ----
    dim3 gm(640, 3);
    k_gemm_mfma<<<gm, 256, 0, stream>>>(Mh3, pre_w, hb3h);
    k_gat_pre3<<<GB, 256, 0, stream>>>(Mh3, hb3h, g1, rp, col, x3h, h1f);

    // ---- gcn layers 2/3 gemms (h1f -> gpair) ----
    dim3 g2(1280, 2);
    k_gemm_f2<<<g2, 256, 0, stream>>>(h1f, gcn_w + 4096, gpair);

    // ---- gat_ori iterations; final one fused with gcn final sum ----
    for (int it = 0; it < 3; it++) {
        k_gemm_mfma<<<gm, 256, 0, stream>>>(x3h, ori_w, hb3h);
        if (it < 2)
            k_gat_ori3<<<GB, 256, 0, stream>>>(hb3h, x3h, rp, col, x3h);
        else
            k_gat_ori3f<<<GB, 256, 0, stream>>>(hb3h, x3h, gpair, x0f, h1f, rp, col, out);
    }
}

// Round 14
// 540.914 us; speedup vs baseline: 1.2330x; 1.0037x over previous
//
#include <hip/hip_runtime.h>
#include <hip/hip_fp16.h>
#include <math.h>

#define NUSER 10000
#define NITEM 30000
#define NN    40000
#define DD    64
#define PLANE ((size_t)NN * DD)

typedef _Float16 hv2 __attribute__((ext_vector_type(2)));
typedef _Float16 half8v __attribute__((ext_vector_type(8)));
typedef float float4v __attribute__((ext_vector_type(4)));
union U2H { unsigned u; hv2 v; __half2 hh; };

#if defined(__has_builtin)
#if __has_builtin(__builtin_amdgcn_fdot2)
#define HAS_FDOT2 1
#endif
#endif

__device__ __forceinline__ float fdot2u(unsigned a, unsigned b, float c) {
#ifdef HAS_FDOT2
    U2H x, y;
    x.u = a;
    y.u = b;
    return __builtin_amdgcn_fdot2(x.v, y.v, c, false);
#else
    U2H x, y;
    x.u = a;
    y.u = b;
    float2 fa = __half22float2(x.hh), fb = __half22float2(y.hh);
    return c + fa.x * fb.x + fa.y * fb.y;
#endif
}

__device__ __forceinline__ float dot8(uint4 a, uint4 b) {
    float d = fdot2u(a.x, b.x, 0.f);
    d = fdot2u(a.y, b.y, d);
    d = fdot2u(a.z, b.z, d);
    d = fdot2u(a.w, b.w, d);
    return d;
}

__device__ __forceinline__ __half2 uh(unsigned u) { U2H x; x.u = u; return x.hh; }
__device__ __forceinline__ unsigned hu(__half2 h) { U2H x; x.hh = h; return x.u; }
__device__ __forceinline__ __half2 h2rx(__half2 v, int m) {
    return __hadd2(v, uh((unsigned)__shfl_xor((int)hu(v), m, 64)));
}

__device__ __forceinline__ float wsum(float v) {
#pragma unroll
    for (int o = 32; o > 0; o >>= 1) v += __shfl_xor(v, o, 64);
    return v;
}
__device__ __forceinline__ float qsum8(float v) {
    v += __shfl_xor(v, 1, 64);
    v += __shfl_xor(v, 2, 64);
    v += __shfl_xor(v, 4, 64);
    return v;
}
// packed: reduce two dot partials at once over the 8-lane group (fp16 sums)
__device__ __forceinline__ float2 qsum8p(float a, float b) {
    __half2 p = __floats2half2_rn(a, b);
    p = h2rx(h2rx(h2rx(p, 1), 2), 4);
    return __half22float2(p);
}
__device__ __forceinline__ float gsum8f(float v) {
    v += __shfl_xor(v, 8, 64);
    v += __shfl_xor(v, 16, 64);
    v += __shfl_xor(v, 32, 64);
    return v;
}

// item-first node order
__device__ __forceinline__ int orderIF(int i) {
    return (i < NITEM) ? (NUSER + i) : (i - NITEM);
}

// ---------------- CSR build ----------------
__global__ void k_hist(const int* ei, int E2, int E, int* cnt, int* posw) {
    int i = blockIdx.x * blockDim.x + threadIdx.x;
    if (i >= E2) return;
    int d = (i < E) ? ei[E + i] : ei[i - E];
    posw[i] = atomicAdd(&cnt[d], 1);
}

__global__ void k_bsum(const int* __restrict__ cnt, int* __restrict__ bsum, int n, int chunk) {
    __shared__ int wsh[4];
    int b = blockIdx.x, tid = threadIdx.x;
    int base = b * chunk, end = min(n, base + chunk);
    int s = 0;
    for (int i = base + tid; i < end; i += 256) s += cnt[i];
#pragma unroll
    for (int o = 32; o > 0; o >>= 1) s += __shfl_xor(s, o, 64);
    if ((tid & 63) == 0) wsh[tid >> 6] = s;
    __syncthreads();
    if (tid == 0) bsum[b] = wsh[0] + wsh[1] + wsh[2] + wsh[3];
}

__global__ void k_bscan(int* bsum, int nb, int* rp_end) {
    int lane = threadIdx.x;
    int v = (lane < nb) ? bsum[lane] : 0;
    int orig = v;
#pragma unroll
    for (int o = 1; o < 64; o <<= 1) {
        int y = __shfl_up(v, o, 64);
        if (lane >= o) v += y;
    }
    if (lane < nb) bsum[lane] = v - orig;
    if (lane == 63) *rp_end = v;
}

__global__ void k_apply(const int* __restrict__ cnt, const int* __restrict__ boff,
                        int* __restrict__ rp, int n, int chunk) {
    __shared__ int buf[256];
    __shared__ int csh;
    int b = blockIdx.x, tid = threadIdx.x;
    int base = b * chunk, end = min(n, base + chunk);
    int carry = boff[b];
    for (int t0 = base; t0 < end; t0 += 256) {
        int i = t0 + tid;
        int v = (i < end) ? cnt[i] : 0;
        int x = v;
        buf[tid] = x;
        __syncthreads();
        for (int o = 1; o < 256; o <<= 1) {
            int y = (tid >= o) ? buf[tid - o] : 0;
            __syncthreads();
            x += y;
            buf[tid] = x;
            __syncthreads();
        }
        if (i < end) rp[i] = carry + x - v;
        __syncthreads();
        if (tid == 255) csh = carry + x;
        __syncthreads();
        carry = csh;
    }
}

__global__ void k_scatter(const int* ei, int E2, int E, const int* rp,
                          const int* __restrict__ posw, int* col) {
    int i = blockIdx.x * blockDim.x + threadIdx.x;
    if (i >= E2) return;
    int j = (i < E) ? i : i - E;
    int s = (i < E) ? ei[j] : ei[E + j];
    int d = (i < E) ? ei[E + j] : ei[j];
    col[rp[d] + posw[i]] = s;
}

// ---------------- node prep ----------------
__global__ void k_prep_pref(const float* __restrict__ pv, const float* __restrict__ pa,
                            const float* __restrict__ pt, __half* __restrict__ M) {
    int t = blockIdx.x * blockDim.x + threadIdx.x;
    int w = t >> 6, lane = t & 63, nw = (gridDim.x * blockDim.x) >> 6;
    for (int r = w; r < NUSER; r += nw) {
        float a = pv[(size_t)r * DD + lane];
        float b = pa[(size_t)r * DD + lane];
        float c = pt[(size_t)r * DD + lane];
        float sa = a * a, sb = b * b, sc = c * c;
#pragma unroll
        for (int o = 32; o > 0; o >>= 1) {
            sa += __shfl_xor(sa, o, 64);
            sb += __shfl_xor(sb, o, 64);
            sc += __shfl_xor(sc, o, 64);
        }
        size_t base = (size_t)r * 3 * DD + lane;
        M[base] = __float2half(a / fmaxf(sqrtf(sa), 1e-12f));
        M[base + DD] = __float2half(b / fmaxf(sqrtf(sb), 1e-12f));
        M[base + 2 * DD] = __float2half(c / fmaxf(sqrtf(sc), 1e-12f));
    }
}

template <int K>
__global__ void k_mlp(const float* __restrict__ feat, const float* __restrict__ W,
                      const float* __restrict__ bias, __half* __restrict__ M, int mo) {
    constexpr int K4 = K / 4;
    __shared__ float4 Wl[K4][DD];
    __shared__ float4 rbuf[4][2][K4];
    int t = threadIdx.x, wib = t >> 6, lane = t & 63;
    for (int i = t; i < DD * K4; i += 256) {
        int c = i / K4, k4 = i - c * K4;
        Wl[k4][c] = *(const float4*)(W + (size_t)c * K + k4 * 4);
    }
    __syncthreads();
    float b = bias[lane];
    const int stride = gridDim.x * 4;
    int r = blockIdx.x * 4 + wib;
    float4 v = {0.f, 0.f, 0.f, 0.f};
    if (r < NITEM && lane < K4) v = *(const float4*)(feat + (size_t)r * K + lane * 4);
    int cur = 0;
    for (; r < NITEM; r += stride) {
        if (lane < K4) rbuf[wib][cur][lane] = v;
        int rn = r + stride;
        if (rn < NITEM && lane < K4) v = *(const float4*)(feat + (size_t)rn * K + lane * 4);
        asm volatile("s_waitcnt lgkmcnt(0)" ::: "memory");
        float acc = b;
#pragma unroll
        for (int k4 = 0; k4 < K4; k4++) {
            float4 x4 = rbuf[wib][cur][k4];
            float4 w4 = Wl[k4][lane];
            acc += x4.x * w4.x + x4.y * w4.y + x4.z * w4.z + x4.w * w4.w;
        }
        float h = acc > 0.f ? acc : 0.01f * acc;
        float n = sqrtf(wsum(h * h));
        M[((size_t)(NUSER + r) * 3 + mo) * DD + lane] = __float2half(h / fmaxf(n, 1e-12f));
        cur ^= 1;
    }
}

// ---------------- MFMA GEMM: fp16 interleaved-3 in/out ----------------
__global__ void k_gemm_mfma(const __half* __restrict__ x3, const float* __restrict__ W3,
                            __half* __restrict__ o3) {
    int mo = blockIdx.y;
    const float* W = W3 + (size_t)mo * 4096;
    int t = threadIdx.x, wv = t >> 6, lane = t & 63;
    int lr = lane & 15, lg = lane >> 4;
    half8v b[4][2];
#pragma unroll
    for (int ct = 0; ct < 4; ct++)
#pragma unroll
        for (int kh = 0; kh < 2; kh++)
#pragma unroll
            for (int i = 0; i < 8; i++)
                b[ct][kh][i] = (_Float16)W[(kh * 32 + lg * 8 + i) * 64 + ct * 16 + lr];
    const int NT = NN / 16;
    for (int rt = blockIdx.x * 4 + wv; rt < NT; rt += gridDim.x * 4) {
        const __half* xr = x3 + ((size_t)(rt * 16 + lr) * 3 + mo) * DD + lg * 8;
        half8v a0 = *(const half8v*)xr;
        half8v a1 = *(const half8v*)(xr + 32);
        float4v acc0 = {0.f, 0.f, 0.f, 0.f}, acc1 = acc0, acc2 = acc0, acc3 = acc0;
        acc0 = __builtin_amdgcn_mfma_f32_16x16x32_f16(a0, b[0][0], acc0, 0, 0, 0);
        acc1 = __builtin_amdgcn_mfma_f32_16x16x32_f16(a0, b[1][0], acc1, 0, 0, 0);
        acc2 = __builtin_amdgcn_mfma_f32_16x16x32_f16(a0, b[2][0], acc2, 0, 0, 0);
        acc3 = __builtin_amdgcn_mfma_f32_16x16x32_f16(a0, b[3][0], acc3, 0, 0, 0);
        acc0 = __builtin_amdgcn_mfma_f32_16x16x32_f16(a1, b[0][1], acc0, 0, 0, 0);
        acc1 = __builtin_amdgcn_mfma_f32_16x16x32_f16(a1, b[1][1], acc1, 0, 0, 0);
        acc2 = __builtin_amdgcn_mfma_f32_16x16x32_f16(a1, b[2][1], acc2, 0, 0, 0);
        acc3 = __builtin_amdgcn_mfma_f32_16x16x32_f16(a1, b[3][1], acc3, 0, 0, 0);
#pragma unroll
        for (int i = 0; i < 4; i++) {
            size_t rbase = ((size_t)(rt * 16 + lg * 4 + i) * 3 + mo) * DD + lr;
            o3[rbase] = __float2half(acc0[i]);
            o3[rbase + 16] = __float2half(acc1[i]);
            o3[rbase + 32] = __float2half(acc2[i]);
            o3[rbase + 48] = __float2half(acc3[i]);
        }
    }
}

__global__ void k_gemm_f2(const float* __restrict__ x, const float* __restrict__ W2,
                          __half* __restrict__ o2) {
    __shared__ float rowbuf[4][DD];
    int mo = blockIdx.y;
    const float* W = W2 + (size_t)mo * 4096;
    int t = threadIdx.x, wib = t >> 6, lane = t & 63;
    float Wc[DD];
#pragma unroll
    for (int k = 0; k < DD; k++) Wc[k] = W[k * DD + lane];
    for (int r = blockIdx.x * 4 + wib; r < NN; r += gridDim.x * 4) {
        rowbuf[wib][lane] = x[(size_t)r * DD + lane];
        asm volatile("s_waitcnt lgkmcnt(0)" ::: "memory");
        float acc = 0.f;
#pragma unroll
        for (int k4 = 0; k4 < DD / 4; k4++) {
            float4 xq = *(const float4*)&rowbuf[wib][k4 * 4];
            acc += xq.x * Wc[k4 * 4] + xq.y * Wc[k4 * 4 + 1] + xq.z * Wc[k4 * 4 + 2] +
                   xq.w * Wc[k4 * 4 + 3];
        }
        o2[((size_t)r * 2 + mo) * DD + lane] = __float2half(acc);
    }
}

__global__ void k_gemm_id(const float* __restrict__ x, const float* __restrict__ W,
                          __half* __restrict__ hout, float* __restrict__ xnorm) {
    __shared__ float rowbuf[4][DD];
    int t = threadIdx.x, wib = t >> 6, lane = t & 63;
    float Wc[DD];
#pragma unroll
    for (int k = 0; k < DD; k++) Wc[k] = W[k * DD + lane];
    for (int r = blockIdx.x * 4 + wib; r < NN; r += gridDim.x * 4) {
        float xv = x[(size_t)r * DD + lane];
        float n = sqrtf(wsum(xv * xv));
        xv /= fmaxf(n, 1e-12f);
        xnorm[(size_t)r * DD + lane] = xv;
        rowbuf[wib][lane] = xv;
        asm volatile("s_waitcnt lgkmcnt(0)" ::: "memory");
        float acc = 0.f;
#pragma unroll
        for (int k4 = 0; k4 < DD / 4; k4++) {
            float4 xq = *(const float4*)&rowbuf[wib][k4 * 4];
            acc += xq.x * Wc[k4 * 4] + xq.y * Wc[k4 * 4 + 1] + xq.z * Wc[k4 * 4 + 2] +
                   xq.w * Wc[k4 * 4 + 3];
        }
        hout[(size_t)r * DD + lane] = __float2half(acc);
    }
}

// ---------------- fused GAT pre + inline gates + gcn layer1 ----------------
__device__ __forceinline__ float gatef(float ssum) {
    float gate = 1.f / (1.f + __expf(-0.5f * ssum));
    return gate > 0.5f ? gate : 1.f;
}

__global__ void k_gat_pre3(const __half* __restrict__ M, const __half* __restrict__ h3,
                           const __half* __restrict__ g1, const int* __restrict__ rp,
                           const int* __restrict__ col, __half* __restrict__ x3h,
                           float* __restrict__ h1f) {
    int t = blockIdx.x * blockDim.x + threadIdx.x;
    int wv = t >> 6, lane = t & 63, nw = (gridDim.x * blockDim.x) >> 6;
    int g = lane >> 3, q = lane & 7;
    const __half2 z = __floats2half2_rn(0.f, 0.f);
    for (int w0 = wv; w0 < NN; w0 += nw) {
        int n = orderIF(w0);
        int e0 = rp[n], e1 = rp[n + 1];
        const uint4* mrow = (const uint4*)(M + (size_t)n * 192);
        uint4 tv = mrow[q], ta = mrow[q + 8], tt = mrow[q + 16];
        const uint4* hrow = (const uint4*)(h3 + (size_t)n * 192);
        uint4 hd0 = hrow[q], hd1 = hrow[q + 8], hd2 = hrow[q + 16];
        float s0 = 0.f, s1 = 0.f, s2 = 0.f;
        __half2 a0[4] = {z, z, z, z}, a1[4] = {z, z, z, z}, a2[4] = {z, z, z, z};
        __half2 ag[4] = {z, z, z, z};
        for (int eb = e0 + g; eb < e1; eb += 8) {
            int sn = col[eb];
            const uint4* srow = (const uint4*)(M + (size_t)sn * 192);
            uint4 sv = srow[q], sa = srow[q + 8], st = srow[q + 16];
            const uint4* hsrow = (const uint4*)(h3 + (size_t)sn * 192);
            uint4 v0 = hsrow[q], v1 = hsrow[q + 8], v2 = hsrow[q + 16];
            uint4 vg = ((const uint4*)(g1 + (size_t)sn * DD))[q];
            float dvp = dot8(tv, sv), dap = dot8(ta, sa), dtp = dot8(tt, st);
            float d0p = dot8(hd0, v0), d1p = dot8(hd1, v1), d2p = dot8(hd2, v2);
            float2 r1_ = qsum8p(dvp, dap);
            float2 r2_ = qsum8p(dtp, d0p);
            float2 r3_ = qsum8p(d1p, d2p);
            float dv = r1_.x, da = r1_.y, dt = r2_.x;
            float d0 = r2_.y, d1 = r3_.x, d2 = r3_.y;
            float ga = gatef(da + dt), gb_ = gatef(dv + dt), gc = gatef(da + dv);
            float sc0 = d0 > 0.f ? d0 : 0.2f * d0;
            float sc1 = d1 > 0.f ? d1 : 0.2f * d1;
            float sc2 = d2 > 0.f ? d2 : 0.2f * d2;
            float p0 = __expf(sc0), p1 = __expf(sc1), p2 = __expf(sc2);
            s0 += p0;
            s1 += p1;
            s2 += p2;
            __half2 ph0 = __float2half2_rn(p0 * ga);
            __half2 ph1 = __float2half2_rn(p1 * gb_);
            __half2 ph2 = __float2half2_rn(p2 * gc);
            a0[0] = __hfma2(ph0, uh(v0.x), a0[0]);
            a0[1] = __hfma2(ph0, uh(v0.y), a0[1]);
            a0[2] = __hfma2(ph0, uh(v0.z), a0[2]);
            a0[3] = __hfma2(ph0, uh(v0.w), a0[3]);
            a1[0] = __hfma2(ph1, uh(v1.x), a1[0]);
            a1[1] = __hfma2(ph1, uh(v1.y), a1[1]);
            a1[2] = __hfma2(ph1, uh(v1.z), a1[2]);
            a1[3] = __hfma2(ph1, uh(v1.w), a1[3]);
            a2[0] = __hfma2(ph2, uh(v2.x), a2[0]);
            a2[1] = __hfma2(ph2, uh(v2.y), a2[1]);
            a2[2] = __hfma2(ph2, uh(v2.z), a2[2]);
            a2[3] = __hfma2(ph2, uh(v2.w), a2[3]);
            ag[0] = __hadd2(ag[0], uh(vg.x));
            ag[1] = __hadd2(ag[1], uh(vg.y));
            ag[2] = __hadd2(ag[2], uh(vg.z));
            ag[3] = __hadd2(ag[3], uh(vg.w));
        }
        s0 = gsum8f(s0);
        s1 = gsum8f(s1);
        s2 = gsum8f(s2);
#pragma unroll
        for (int j = 0; j < 4; j++) {
            a0[j] = h2rx(h2rx(h2rx(a0[j], 8), 16), 32);
            a1[j] = h2rx(h2rx(h2rx(a1[j], 8), 16), 32);
            a2[j] = h2rx(h2rx(h2rx(a2[j], 8), 16), 32);
            ag[j] = h2rx(h2rx(h2rx(ag[j], 8), 16), 32);
        }
        float i0 = 1.f / (s0 + 1e-16f), i1 = 1.f / (s1 + 1e-16f), i2 = 1.f / (s2 + 1e-16f);
        float o0[8], o1[8], o2[8];
#pragma unroll
        for (int j = 0; j < 4; j++) {
            float2 f0 = __half22float2(a0[j]);
            float2 f1 = __half22float2(a1[j]);
            float2 f2 = __half22float2(a2[j]);
            o0[2 * j] = f0.x * i0;
            o0[2 * j + 1] = f0.y * i0;
            o1[2 * j] = f1.x * i1;
            o1[2 * j + 1] = f1.y * i1;
            o2[2 * j] = f2.x * i2;
            o2[2 * j + 1] = f2.y * i2;
        }
        float n0 = 0.f, n1 = 0.f, n2 = 0.f;
#pragma unroll
        for (int k = 0; k < 8; k++) {
            n0 += o0[k] * o0[k];
            n1 += o1[k] * o1[k];
            n2 += o2[k] * o2[k];
        }
        n0 = qsum8(n0);
        n1 = qsum8(n1);
        n2 = qsum8(n2);
        float r0 = 1.f / fmaxf(sqrtf(n0), 1e-12f);
        float r1 = 1.f / fmaxf(sqrtf(n1), 1e-12f);
        float r2 = 1.f / fmaxf(sqrtf(n2), 1e-12f);
        if (g == 0) {
            uint4* orow = (uint4*)(x3h + (size_t)n * 192);
            uint4 w0_, w1_, w2_;
            w0_.x = hu(__floats2half2_rn(o0[0] * r0, o0[1] * r0));
            w0_.y = hu(__floats2half2_rn(o0[2] * r0, o0[3] * r0));
            w0_.z = hu(__floats2half2_rn(o0[4] * r0, o0[5] * r0));
            w0_.w = hu(__floats2half2_rn(o0[6] * r0, o0[7] * r0));
            w1_.x = hu(__floats2half2_rn(o1[0] * r1, o1[1] * r1));
            w1_.y = hu(__floats2half2_rn(o1[2] * r1, o1[3] * r1));
            w1_.z = hu(__floats2half2_rn(o1[4] * r1, o1[5] * r1));
            w1_.w = hu(__floats2half2_rn(o1[6] * r1, o1[7] * r1));
            w2_.x = hu(__floats2half2_rn(o2[0] * r2, o2[1] * r2));
            w2_.y = hu(__floats2half2_rn(o2[2] * r2, o2[3] * r2));
            w2_.z = hu(__floats2half2_rn(o2[4] * r2, o2[5] * r2));
            w2_.w = hu(__floats2half2_rn(o2[6] * r2, o2[7] * r2));
            orow[q] = w0_;
            orow[q + 8] = w1_;
            orow[q + 16] = w2_;
            float og[8];
#pragma unroll
            for (int j = 0; j < 4; j++) {
                float2 f = __half22float2(ag[j]);
                og[2 * j] = f.x > 0.f ? f.x : 0.01f * f.x;
                og[2 * j + 1] = f.y > 0.f ? f.y : 0.01f * f.y;
            }
            float* ob = h1f + (size_t)n * DD + q * 8;
            *(float4*)(ob) = make_float4(og[0], og[1], og[2], og[3]);
            *(float4*)(ob + 4) = make_float4(og[4], og[5], og[6], og[7]);
        }
    }
}

// ---------------- fused 3-modality GAT ori (intermediate iterations) ----------------
__global__ void k_gat_ori3(const __half* __restrict__ h3, const __half* __restrict__ x3h,
                           const int* __restrict__ rp, const int* __restrict__ col,
                           __half* __restrict__ xout) {
    int t = blockIdx.x * blockDim.x + threadIdx.x;
    int wv = t >> 6, lane = t & 63, nw = (gridDim.x * blockDim.x) >> 6;
    int g = lane >> 3, q = lane & 7;
    const __half2 z = __floats2half2_rn(0.f, 0.f);
    for (int w0 = wv; w0 < NN; w0 += nw) {
        int n = orderIF(w0);
        int e0 = rp[n], e1 = rp[n + 1];
        const uint4* hrow = (const uint4*)(h3 + (size_t)n * 192);
        uint4 hd0 = hrow[q], hd1 = hrow[q + 8], hd2 = hrow[q + 16];
        float s0 = 0.f, s1 = 0.f, s2 = 0.f;
        __half2 a0[4] = {z, z, z, z}, a1[4] = {z, z, z, z}, a2[4] = {z, z, z, z};
#pragma unroll 2
        for (int eb = e0 + g; eb < e1; eb += 8) {
            int sn = col[eb];
            const uint4* srow = (const uint4*)(h3 + (size_t)sn * 192);
            uint4 v0 = srow[q], v1 = srow[q + 8], v2 = srow[q + 16];
            float d0p = dot8(hd0, v0), d1p = dot8(hd1, v1), d2p = dot8(hd2, v2);
            float2 r01 = qsum8p(d0p, d1p);
            float d0 = r01.x, d1 = r01.y;
            float d2 = qsum8(d2p);
            float sc0 = d0 > 0.f ? d0 : 0.2f * d0;
            float sc1 = d1 > 0.f ? d1 : 0.2f * d1;
            float sc2 = d2 > 0.f ? d2 : 0.2f * d2;
            float p0 = __expf(sc0), p1 = __expf(sc1), p2 = __expf(sc2);
            s0 += p0;
            s1 += p1;
            s2 += p2;
            __half2 ph0 = __float2half2_rn(p0);
            __half2 ph1 = __float2half2_rn(p1);
            __half2 ph2 = __float2half2_rn(p2);
            a0[0] = __hfma2(ph0, uh(v0.x), a0[0]);
            a0[1] = __hfma2(ph0, uh(v0.y), a0[1]);
            a0[2] = __hfma2(ph0, uh(v0.z), a0[2]);
            a0[3] = __hfma2(ph0, uh(v0.w), a0[3]);
            a1[0] = __hfma2(ph1, uh(v1.x), a1[0]);
            a1[1] = __hfma2(ph1, uh(v1.y), a1[1]);
            a1[2] = __hfma2(ph1, uh(v1.z), a1[2]);
            a1[3] = __hfma2(ph1, uh(v1.w), a1[3]);
            a2[0] = __hfma2(ph2, uh(v2.x), a2[0]);
            a2[1] = __hfma2(ph2, uh(v2.y), a2[1]);
            a2[2] = __hfma2(ph2, uh(v2.z), a2[2]);
            a2[3] = __hfma2(ph2, uh(v2.w), a2[3]);
        }
        s0 = gsum8f(s0);
        s1 = gsum8f(s1);
        s2 = gsum8f(s2);
#pragma unroll
        for (int j = 0; j < 4; j++) {
            a0[j] = h2rx(h2rx(h2rx(a0[j], 8), 16), 32);
            a1[j] = h2rx(h2rx(h2rx(a1[j], 8), 16), 32);
            a2[j] = h2rx(h2rx(h2rx(a2[j], 8), 16), 32);
        }
        float i0 = 1.f / (s0 + 1e-16f), i1 = 1.f / (s1 + 1e-16f), i2 = 1.f / (s2 + 1e-16f);
        const uint4* xrow = (const uint4*)(x3h + (size_t)n * 192);
        uint4 xr0 = xrow[q], xr1 = xrow[q + 8], xr2 = xrow[q + 16];
        float o0[8], o1[8], o2[8];
#pragma unroll
        for (int j = 0; j < 4; j++) {
            float2 f0 = __half22float2(a0[j]);
            float2 f1 = __half22float2(a1[j]);
            float2 f2 = __half22float2(a2[j]);
            float2 xf0 = __half22float2(uh(j == 0 ? xr0.x : j == 1 ? xr0.y : j == 2 ? xr0.z : xr0.w));
            float2 xf1 = __half22float2(uh(j == 0 ? xr1.x : j == 1 ? xr1.y : j == 2 ? xr1.z : xr1.w));
            float2 xf2 = __half22float2(uh(j == 0 ? xr2.x : j == 1 ? xr2.y : j == 2 ? xr2.z : xr2.w));
            o0[2 * j] = xf0.x + f0.x * i0;
            o0[2 * j + 1] = xf0.y + f0.y * i0;
            o1[2 * j] = xf1.x + f1.x * i1;
            o1[2 * j + 1] = xf1.y + f1.y * i1;
            o2[2 * j] = xf2.x + f2.x * i2;
            o2[2 * j + 1] = xf2.y + f2.y * i2;
        }
        float n0 = 0.f, n1 = 0.f, n2 = 0.f;
#pragma unroll
        for (int k = 0; k < 8; k++) {
            n0 += o0[k] * o0[k];
            n1 += o1[k] * o1[k];
            n2 += o2[k] * o2[k];
        }
        n0 = qsum8(n0);
        n1 = qsum8(n1);
        n2 = qsum8(n2);
        float r0 = 1.f / fmaxf(sqrtf(n0), 1e-12f);
        float r1 = 1.f / fmaxf(sqrtf(n1), 1e-12f);
        float r2 = 1.f / fmaxf(sqrtf(n2), 1e-12f);
        if (g == 0) {
            uint4* orow = (uint4*)(xout + (size_t)n * 192);
            uint4 w0_, w1_, w2_;
            w0_.x = hu(__floats2half2_rn(o0[0] * r0, o0[1] * r0));
            w0_.y = hu(__floats2half2_rn(o0[2] * r0, o0[3] * r0));
            w0_.z = hu(__floats2half2_rn(o0[4] * r0, o0[5] * r0));
            w0_.w = hu(__floats2half2_rn(o0[6] * r0, o0[7] * r0));
            w1_.x = hu(__floats2half2_rn(o1[0] * r1, o1[1] * r1));
            w1_.y = hu(__floats2half2_rn(o1[2] * r1, o1[3] * r1));
            w1_.z = hu(__floats2half2_rn(o1[4] * r1, o1[5] * r1));
            w1_.w = hu(__floats2half2_rn(o1[6] * r1, o1[7] * r1));
            w2_.x = hu(__floats2half2_rn(o2[0] * r2, o2[1] * r2));
            w2_.y = hu(__floats2half2_rn(o2[2] * r2, o2[3] * r2));
            w2_.z = hu(__floats2half2_rn(o2[4] * r2, o2[5] * r2));
            w2_.w = hu(__floats2half2_rn(o2[6] * r2, o2[7] * r2));
            orow[q] = w0_;
            orow[q + 8] = w1_;
            orow[q + 16] = w2_;
        }
    }
}

// ---------------- final GAT ori fused with gcn layers 2+3 + 4-way sum ----------------
__global__ void k_gat_ori3f(const __half* __restrict__ h3, const __half* __restrict__ x3h,
                            const __half* __restrict__ gp, const float* __restrict__ x0,
                            const float* __restrict__ h1, const int* __restrict__ rp,
                            const int* __restrict__ col, float* __restrict__ out) {
    int t = blockIdx.x * blockDim.x + threadIdx.x;
    int wv = t >> 6, lane = t & 63, nw = (gridDim.x * blockDim.x) >> 6;
    int g = lane >> 3, q = lane & 7;
    const __half2 z = __floats2half2_rn(0.f, 0.f);
    for (int w0 = wv; w0 < NN; w0 += nw) {
        int n = orderIF(w0);
        int e0 = rp[n], e1 = rp[n + 1];
        const uint4* hrow = (const uint4*)(h3 + (size_t)n * 192);
        uint4 hd0 = hrow[q], hd1 = hrow[q + 8], hd2 = hrow[q + 16];
        float s0 = 0.f, s1 = 0.f, s2 = 0.f;
        __half2 a0[4] = {z, z, z, z}, a1[4] = {z, z, z, z}, a2[4] = {z, z, z, z};
        __half2 aA[4] = {z, z, z, z}, aB[4] = {z, z, z, z};
        for (int eb = e0 + g; eb < e1; eb += 8) {
            int sn = col[eb];
            const uint4* srow = (const uint4*)(h3 + (size_t)sn * 192);
            uint4 v0 = srow[q], v1 = srow[q + 8], v2 = srow[q + 16];
            const uint4* gbase = (const uint4*)(gp + (size_t)sn * 128);
            uint4 vA = gbase[q], vB = gbase[q + 8];
            float d0p = dot8(hd0, v0), d1p = dot8(hd1, v1), d2p = dot8(hd2, v2);
            float2 r01 = qsum8p(d0p, d1p);
            float d0 = r01.x, d1 = r01.y;
            float d2 = qsum8(d2p);
            float sc0 = d0 > 0.f ? d0 : 0.2f * d0;
            float sc1 = d1 > 0.f ? d1 : 0.2f * d1;
            float sc2 = d2 > 0.f ? d2 : 0.2f * d2;
            float p0 = __expf(sc0), p1 = __expf(sc1), p2 = __expf(sc2);
            s0 += p0;
            s1 += p1;
            s2 += p2;
            __half2 ph0 = __float2half2_rn(p0);
            __half2 ph1 = __float2half2_rn(p1);
            __half2 ph2 = __float2half2_rn(p2);
            a0[0] = __hfma2(ph0, uh(v0.x), a0[0]);
            a0[1] = __hfma2(ph0, uh(v0.y), a0[1]);
            a0[2] = __hfma2(ph0, uh(v0.z), a0[2]);
            a0[3] = __hfma2(ph0, uh(v0.w), a0[3]);
            a1[0] = __hfma2(ph1, uh(v1.x), a1[0]);
            a1[1] = __hfma2(ph1, uh(v1.y), a1[1]);
            a1[2] = __hfma2(ph1, uh(v1.z), a1[2]);
            a1[3] = __hfma2(ph1, uh(v1.w), a1[3]);
            a2[0] = __hfma2(ph2, uh(v2.x), a2[0]);
            a2[1] = __hfma2(ph2, uh(v2.y), a2[1]);
            a2[2] = __hfma2(ph2, uh(v2.z), a2[2]);
            a2[3] = __hfma2(ph2, uh(v2.w), a2[3]);
            aA[0] = __hadd2(aA[0], uh(vA.x));
            aA[1] = __hadd2(aA[1], uh(vA.y));
            aA[2] = __hadd2(aA[2], uh(vA.z));
            aA[3] = __hadd2(aA[3], uh(vA.w));
            aB[0] = __hadd2(aB[0], uh(vB.x));
            aB[1] = __hadd2(aB[1], uh(vB.y));
            aB[2] = __hadd2(aB[2], uh(vB.z));
            aB[3] = __hadd2(aB[3], uh(vB.w));
        }
        s0 = gsum8f(s0);
        s1 = gsum8f(s1);
        s2 = gsum8f(s2);
#pragma unroll
        for (int j = 0; j < 4; j++) {
            a0[j] = h2rx(h2rx(h2rx(a0[j], 8), 16), 32);
            a1[j] = h2rx(h2rx(h2rx(a1[j], 8), 16), 32);
            a2[j] = h2rx(h2rx(h2rx(a2[j], 8), 16), 32);
            aA[j] = h2rx(h2rx(h2rx(aA[j], 8), 16), 32);
            aB[j] = h2rx(h2rx(h2rx(aB[j], 8), 16), 32);
        }
        float i0 = 1.f / (s0 + 1e-16f), i1 = 1.f / (s1 + 1e-16f), i2 = 1.f / (s2 + 1e-16f);
        const uint4* xrow = (const uint4*)(x3h + (size_t)n * 192);
        uint4 xr0 = xrow[q], xr1 = xrow[q + 8], xr2 = xrow[q + 16];
        float o0[8], o1[8], o2[8];
#pragma unroll
        for (int j = 0; j < 4; j++) {
            float2 f0 = __half22float2(a0[j]);
            float2 f1 = __half22float2(a1[j]);
            float2 f2 = __half22float2(a2[j]);
            float2 xf0 = __half22float2(uh(j == 0 ? xr0.x : j == 1 ? xr0.y : j == 2 ? xr0.z : xr0.w));
            float2 xf1 = __half22float2(uh(j == 0 ? xr1.x : j == 1 ? xr1.y : j == 2 ? xr1.z : xr1.w));
            float2 xf2 = __half22float2(uh(j == 0 ? xr2.x : j == 1 ? xr2.y : j == 2 ? xr2.z : xr2.w));
            o0[2 * j] = xf0.x + f0.x * i0;
            o0[2 * j + 1] = xf0.y + f0.y * i0;
            o1[2 * j] = xf1.x + f1.x * i1;
            o1[2 * j + 1] = xf1.y + f1.y * i1;
            o2[2 * j] = xf2.x + f2.x * i2;
            o2[2 * j + 1] = xf2.y + f2.y * i2;
        }
        float n0 = 0.f, n1 = 0.f, n2 = 0.f;
#pragma unroll
        for (int k = 0; k < 8; k++) {
            n0 += o0[k] * o0[k];
            n1 += o1[k] * o1[k];
            n2 += o2[k] * o2[k];
        }
        n0 = qsum8(n0);
        n1 = qsum8(n1);
        n2 = qsum8(n2);
        float r0 = 1.f / fmaxf(sqrtf(n0), 1e-12f);
        float r1 = 1.f / fmaxf(sqrtf(n1), 1e-12f);
        float r2 = 1.f / fmaxf(sqrtf(n2), 1e-12f);
        if (g == 0) {
            float* ob = out + (size_t)n * 256 + q * 8;
            const float* p0 = x0 + (size_t)n * DD + q * 8;
            const float* p1 = h1 + (size_t)n * DD + q * 8;
            float4 v0a = *(const float4*)(p0), v0b = *(const float4*)(p0 + 4);
            float4 v1a = *(const float4*)(p1), v1b = *(const float4*)(p1 + 4);
            float og[8];
#pragma unroll
            for (int j = 0; j < 4; j++) {
                float2 fA = __half22float2(aA[j]);
                float2 fB = __half22float2(aB[j]);
                float hx = fA.x > 0.f ? fA.x : 0.01f * fA.x;
                float hy = fA.y > 0.f ? fA.y : 0.01f * fA.y;
                og[2 * j] = hx + fB.x;
                og[2 * j + 1] = hy + fB.y;
            }
            *(float4*)(ob) = make_float4(og[0] + v0a.x + v1a.x, og[1] + v0a.y + v1a.y,
                                         og[2] + v0a.z + v1a.z, og[3] + v0a.w + v1a.w);
            *(float4*)(ob + 4) = make_float4(og[4] + v0b.x + v1b.x, og[5] + v0b.y + v1b.y,
                                             og[6] + v0b.z + v1b.z, og[7] + v0b.w + v1b.w);
            *(float4*)(ob + 64) = make_float4(o0[0] * r0, o0[1] * r0, o0[2] * r0, o0[3] * r0);
            *(float4*)(ob + 68) = make_float4(o0[4] * r0, o0[5] * r0, o0[6] * r0, o0[7] * r0);
            *(float4*)(ob + 128) = make_float4(o1[0] * r1, o1[1] * r1, o1[2] * r1, o1[3] * r1);
            *(float4*)(ob + 132) = make_float4(o1[4] * r1, o1[5] * r1, o1[6] * r1, o1[7] * r1);
            *(float4*)(ob + 192) = make_float4(o2[0] * r2, o2[1] * r2, o2[2] * r2, o2[3] * r2);
            *(float4*)(ob + 196) = make_float4(o2[4] * r2, o2[5] * r2, o2[6] * r2, o2[7] * r2);
        }
    }
}

extern "C" void kernel_launch(void* const* d_in, const int* in_sizes, int n_in,
                              void* d_out, int out_size, void* d_ws, size_t ws_size,
                              hipStream_t stream) {
    const int* ei       = (const int*)d_in[0];
    const float* v_feat = (const float*)d_in[1];
    const float* a_feat = (const float*)d_in[2];
    const float* t_feat = (const float*)d_in[3];
    const float* pref_v = (const float*)d_in[4];
    const float* pref_a = (const float*)d_in[5];
    const float* pref_t = (const float*)d_in[6];
    const float* mlp_v_w = (const float*)d_in[7];
    const float* mlp_v_b = (const float*)d_in[8];
    const float* mlp_a_w = (const float*)d_in[9];
    const float* mlp_a_b = (const float*)d_in[10];
    const float* mlp_t_w = (const float*)d_in[11];
    const float* mlp_t_b = (const float*)d_in[12];
    const float* pre_w  = (const float*)d_in[13];
    const float* ori_w  = (const float*)d_in[14];
    const float* gcn_w  = (const float*)d_in[15];
    const float* id_emb = (const float*)d_in[16];
    float* out = (float*)d_out;

    const int E2 = in_sizes[0];
    const int E  = E2 / 2;

    char* w = (char*)d_ws;
    auto alloc = [&](size_t bytes) -> void* {
        void* p = (void*)w;
        w += (bytes + 255) & ~(size_t)255;
        return p;
    };
    int* cnt  = (int*)alloc((size_t)NN * 4);
    int* rp   = (int*)alloc((size_t)(NN + 1) * 4);
    int* bsum = (int*)alloc(256);
    int* col  = (int*)alloc((size_t)E2 * 4);
    int* posw = (int*)alloc((size_t)E2 * 4);
    __half* Mh3  = (__half*)alloc(3 * PLANE * 2);
    __half* hb3h = (__half*)alloc(3 * PLANE * 2);
    __half* x3h  = (__half*)alloc(3 * PLANE * 2);
    __half* g1   = (__half*)alloc(PLANE * 2);
    __half* gpair = (__half*)alloc(2 * PLANE * 2);
    float* x0f = (float*)alloc(PLANE * 4);
    float* h1f = (float*)alloc(PLANE * 4);

    // ---- CSR by destination ----
    const int NBLK = 64, CHUNK = (NN + NBLK - 1) / NBLK;
    hipMemsetAsync(cnt, 0, (size_t)NN * 4, stream);
    k_hist<<<(E2 + 255) / 256, 256, 0, stream>>>(ei, E2, E, cnt, posw);
    k_bsum<<<NBLK, 256, 0, stream>>>(cnt, bsum, NN, CHUNK);
    k_bscan<<<1, 64, 0, stream>>>(bsum, NBLK, rp + NN);
    k_apply<<<NBLK, 256, 0, stream>>>(cnt, bsum, rp, NN, CHUNK);
    k_scatter<<<(E2 + 255) / 256, 256, 0, stream>>>(ei, E2, E, rp, posw, col);

    // ---- node tables (interleaved fp16) ----
    k_prep_pref<<<640, 256, 0, stream>>>(pref_v, pref_a, pref_t, Mh3);
    k_mlp<128><<<1024, 256, 0, stream>>>(v_feat, mlp_v_w, mlp_v_b, Mh3, 0);
    k_mlp<128><<<1024, 256, 0, stream>>>(a_feat, mlp_a_w, mlp_a_b, Mh3, 1);
    k_mlp<100><<<1024, 256, 0, stream>>>(t_feat, mlp_t_w, mlp_t_b, Mh3, 2);

    const int GB = (NN + 3) / 4;

    // ---- gcn layer 0 ----
    k_gemm_id<<<1280, 256, 0, stream>>>(id_emb, gcn_w, g1, x0f);

    // ---- gat_pre fused with gates + gcn conv1 ----
    dim3 gm(640, 3);
    k_gemm_mfma<<<gm, 256, 0, stream>>>(Mh3, pre_w, hb3h);
    k_gat_pre3<<<GB, 256, 0, stream>>>(Mh3, hb3h, g1, rp, col, x3h, h1f);

    // ---- gcn layers 2/3 gemms ----
    dim3 g2(1280, 2);
    k_gemm_f2<<<g2, 256, 0, stream>>>(h1f, gcn_w + 4096, gpair);

    // ---- gat_ori iterations; final fused with gcn sum ----
    for (int it = 0; it < 3; it++) {
        k_gemm_mfma<<<gm, 256, 0, stream>>>(x3h, ori_w, hb3h);
        if (it < 2)
            k_gat_ori3<<<GB, 256, 0, stream>>>(hb3h, x3h, rp, col, x3h);
        else
            k_gat_ori3f<<<GB, 256, 0, stream>>>(hb3h, x3h, gpair, x0f, h1f, rp, col, out);
    }
}